// Round 6
// baseline (1313.819 us; speedup 1.0000x reference)
//
#include <hip/hip_runtime.h>
#include <hip/hip_bf16.h>

typedef _Float16 hf;
typedef short    s8v  __attribute__((ext_vector_type(8)));
typedef _Float16 h8v  __attribute__((ext_vector_type(8)));
typedef float    f32x4 __attribute__((ext_vector_type(4)));

#define DEVINL __device__ __forceinline__

DEVINL unsigned short f2h_bits(float f) { return __builtin_bit_cast(unsigned short, (hf)f); }
DEVINL float h2f_bits(unsigned short u) { return (float)__builtin_bit_cast(hf, u); }

// ---------------------------------------------------------------- arena
static constexpr size_t OFF_SA    = 0;           // f1 packed  [2][4096][32] hf
static constexpr size_t OFF_F2S   = 524288;      // f2 sampled [162][4096][32] hf
static constexpr size_t OFF_E1    = 42991616;    // e1out [162][4096][48]
static constexpr size_t OFF_E2    = 106692608;   // e2out [162][4096][64]
static constexpr size_t OFF_E3    = 42991616;    // e3out [162][4096][32] (reuse E1)
static constexpr size_t OFF_X1    = 85458944;    // x1 [162][4096][96]
static constexpr size_t OFF_X2    = 524288;      // x2 [162][1024][128]
static constexpr size_t OFF_X3    = 85458944;    // x3 [162][1024][128]
static constexpr size_t OFF_X4    = 524288;      // x4 [162][1024][64]
static constexpr size_t OFF_XD    = 127926272;   // xd [162][4096][32]
static constexpr size_t OFF_SCORE = 524288;      // f32 [2][81][4096]
static constexpr size_t OFF_STATS = 212860928;   // f32 2560
static constexpr size_t OFF_WC1   = 212871168;
static constexpr size_t OFF_WC2   = 212981760;
static constexpr size_t OFF_WC3   = 213202944;
static constexpr size_t OFF_WC4   = 213497856;
static constexpr size_t OFF_WDC   = 213645312;
static constexpr size_t OFF_WC5   = 213710848;
static constexpr size_t OFF_WE1   = 213720064;
static constexpr size_t OFF_WE2   = 213726208;
static constexpr size_t OFF_WE3   = 213734400;
static constexpr size_t OFF_DT1   = 213738496;
static constexpr size_t OFF_DTE   = 213745408;
static constexpr size_t OFF_F2CLF = 213746048;   // f2 packed [2][4096][32] f32 (1 MB)

// ---------------------------------------------------------------- prepack
__global__ void prepack(const float* __restrict__ src, hf* __restrict__ dst,
                        int COr, int COP, int CINr, int CINsrc, int KP, int TAPS) {
  const int idx = blockIdx.x * 256 + threadIdx.x;
  const int total = TAPS * COP * KP;
  if (idx >= total) return;
  const int k = idx % KP;
  const int r = idx / KP;
  const int co = r % COP;
  const int t = r / COP;
  float v = 0.f;
  if (co < COr && k < CINr) v = src[((size_t)co * CINsrc + k) * TAPS + t];
  dst[idx] = (hf)v;
}

__global__ void dtab1_kernel(const float* __restrict__ w1, float* __restrict__ dtab) {
  const int idx = blockIdx.x * 256 + threadIdx.x;  // 96*9*2
  if (idx >= 96 * 9 * 2) return;
  const int c = idx & 1;
  const int r = idx >> 1;
  const int pat = r % 9;
  const int co = r / 9;
  const int rc = pat / 3, cc = pat % 3;
  const int kh0 = (rc == 0) ? 1 : 0, kh1 = (rc == 2) ? 1 : 2;
  const int kw0 = (cc == 0) ? 1 : 0, kw1 = (cc == 2) ? 1 : 2;
  float s = 0.f;
  for (int kh = kh0; kh <= kh1; ++kh)
    for (int kw = kw0; kw <= kw1; ++kw)
      s += w1[((size_t)(co * 66 + 64 + c) * 3 + kh) * 3 + kw];
  dtab[(co * 9 + pat) * 2 + c] = s;
}

__global__ void dtabE_kernel(const float* __restrict__ e1w, float* __restrict__ dtE) {
  const int co = threadIdx.x;
  if (co < 48) {
    dtE[co * 2 + 0] = e1w[co * 66 + 64];
    dtE[co * 2 + 1] = e1w[co * 66 + 65];
  }
}

// ---------------------------------------------------------------- input builders
__global__ __launch_bounds__(256) void packf1(const float* __restrict__ f1, hf* __restrict__ sA) {
  const int gid = blockIdx.x * 256 + threadIdx.x;  // 2*4096
  const int b = gid >> 12, pix = gid & 4095;
  unsigned words[16];
#pragma unroll
  for (int c = 0; c < 32; c += 2) {
    const float v0 = f1[((size_t)(b * 32 + c)) * 4096 + pix];
    const float v1 = f1[((size_t)(b * 32 + c + 1)) * 4096 + pix];
    words[c >> 1] = (unsigned)f2h_bits(v0) | ((unsigned)f2h_bits(v1) << 16);
  }
  uint4* dst = (uint4*)(sA + (size_t)gid * 32);
#pragma unroll
  for (int i = 0; i < 4; ++i)
    dst[i] = make_uint4(words[4 * i], words[4 * i + 1], words[4 * i + 2], words[4 * i + 3]);
}

__global__ __launch_bounds__(256) void packf2f32(const float* __restrict__ f2,
                                                 float* __restrict__ dst) {
  const int gid = blockIdx.x * 256 + threadIdx.x;  // 2*4096
  const int b = gid >> 12, pix = gid & 4095;
  float* op = dst + (size_t)gid * 32;
#pragma unroll
  for (int c = 0; c < 32; c += 4) {
    float4 v;
    v.x = f2[((size_t)(b * 32 + c + 0)) * 4096 + pix];
    v.y = f2[((size_t)(b * 32 + c + 1)) * 4096 + pix];
    v.z = f2[((size_t)(b * 32 + c + 2)) * 4096 + pix];
    v.w = f2[((size_t)(b * 32 + c + 3)) * 4096 + pix];
    *(float4*)(op + c) = v;
  }
}

__global__ __launch_bounds__(256) void sample2(const float* __restrict__ f2clf,
                                               const float* __restrict__ coords,
                                               hf* __restrict__ f2s) {
  const int gid = blockIdx.x * 256 + threadIdx.x;  // 162*4096
  const int n = gid >> 12, pix = gid & 4095;
  const int b = n / 81, ij = n - b * 81;
  const float di = (float)(ij / 9) - 4.f, dj = (float)(ij % 9) - 4.f;
  const float x = coords[((size_t)(b * 2 + 0)) * 4096 + pix] + di;
  const float y = coords[((size_t)(b * 2 + 1)) * 4096 + pix] + dj;
  const float x0f = floorf(x), y0f = floorf(y);
  const int x0 = (int)x0f, y0 = (int)y0f;
  const float wx1 = x - x0f, wx0 = 1.f - wx1;
  const float wy1 = y - y0f, wy0 = 1.f - wy1;
  const bool vx0 = (unsigned)x0 < 64u, vx1 = (unsigned)(x0 + 1) < 64u;
  const bool vy0 = (unsigned)y0 < 64u, vy1 = (unsigned)(y0 + 1) < 64u;
  const int x0c = min(max(x0, 0), 63), x1c = min(max(x0 + 1, 0), 63);
  const int y0c = min(max(y0, 0), 63), y1c = min(max(y0 + 1, 0), 63);
  const float w00 = (vy0 && vx0) ? wy0 * wx0 : 0.f;
  const float w01 = (vy0 && vx1) ? wy0 * wx1 : 0.f;
  const float w10 = (vy1 && vx0) ? wy1 * wx0 : 0.f;
  const float w11 = (vy1 && vx1) ? wy1 * wx1 : 0.f;
  const float* fb = f2clf + (size_t)b * 4096 * 32;
  const float* p00 = fb + (size_t)(y0c * 64 + x0c) * 32;
  const float* p01 = fb + (size_t)(y0c * 64 + x1c) * 32;
  const float* p10 = fb + (size_t)(y1c * 64 + x0c) * 32;
  const float* p11 = fb + (size_t)(y1c * 64 + x1c) * 32;
  unsigned words[16];
#pragma unroll
  for (int ch = 0; ch < 16; ++ch) {
    const float2 a  = *(const float2*)(p00 + ch * 2);
    const float2 bb = *(const float2*)(p01 + ch * 2);
    const float2 c  = *(const float2*)(p10 + ch * 2);
    const float2 d  = *(const float2*)(p11 + ch * 2);
    const float v0 = w00 * a.x + w01 * bb.x + w10 * c.x + w11 * d.x;
    const float v1 = w00 * a.y + w01 * bb.y + w10 * c.y + w11 * d.y;
    words[ch] = (unsigned)f2h_bits(v0) | ((unsigned)f2h_bits(v1) << 16);
  }
  uint4* dst = (uint4*)(f2s + (size_t)gid * 32);
#pragma unroll
  for (int i = 0; i < 4; ++i)
    dst[i] = make_uint4(words[4 * i], words[4 * i + 1], words[4 * i + 2], words[4 * i + 3]);
}

// ---------------------------------------------------------------- MFMA conv template
// GEOM: 0 = 3x3 s1 | 1 = 3x3 s2 (64->32) | 2 = deconv parity | 3 = 1x1 (DIRECT, no LDS)
// EPI : 0 = raw store + BN stats | 1 = bias+relu | 2 = bias | 3 = conv5 cost f32
// Activations channel-last [n][pix][G] hf; weights [tap][COP][KP] hf.
// LDS: plane-major with padded plane stride PSTR=NSLOT+1 (conflict-free write+read).
// Pipeline: {barrier; ds_write(rbuf); barrier; prefetch next slab; MFMA}.
template <int GEOM, int EPI, bool DUAL, int G, int KP, int COP, int COB, int MFR,
          int IMGO, int IMGI, int PIXROWS, int WPIX, bool DELTA>
__global__ __launch_bounds__(256) void mconv(
    const hf* __restrict__ src1, const hf* __restrict__ src0,
    const hf* __restrict__ wp, const float* __restrict__ bias,
    const float* __restrict__ dtab, float* __restrict__ statL,
    hf* __restrict__ outB, float* __restrict__ outF) {
  constexpr bool DIRECT = (GEOM == 3);
  constexpr int TAPS  = (GEOM == 2) ? 4 : (GEOM == 3) ? 1 : 9;
  constexpr int TR    = (GEOM == 1) ? (2 * PIXROWS + 1) : (GEOM == 3) ? 1 : (PIXROWS + 2);
  constexpr int TC    = (GEOM == 1) ? 65 : (GEOM == 3) ? 1 : (IMGI + 2);
  constexpr int NSLOT = TR * TC;
  constexpr int PSTR  = NSLOT + 1;
  constexpr int NCH   = KP / 32;
  constexpr int NPIXI = IMGI * IMGI;
  constexpr int NPIXO = (GEOM == 2) ? 4096 : IMGO * IMGO;
  constexpr int NCHUNK = NSLOT * 4;
  constexpr int CPT   = (NCHUNK + 255) / 256;
  constexpr int LDSE  = DIRECT ? 64 : 4 * PSTR * 8;

  __shared__ __align__(16) hf lds[LDSE];

  const int tid = threadIdx.x;
  const int wid = tid >> 6, lane = tid & 63, lg = lane >> 4, ln = lane & 15;
  const int n = blockIdx.z, b = n / 81, ij = n - b * 81;
  const int r0 = blockIdx.x * PIXROWS;
  const int qq = (GEOM == 2) ? (int)(blockIdx.y >> 1) : 0;
  const int pp = (GEOM == 2) ? (int)(blockIdx.y & 1) : 0;
  const int co0 = (GEOM == 2) ? 0 : (int)blockIdx.y * (MFR * 16);

  f32x4 acc[MFR][WPIX];
#pragma unroll
  for (int mf = 0; mf < MFR; ++mf)
#pragma unroll
    for (int pf = 0; pf < WPIX; ++pf) acc[mf][pf] = (f32x4){0.f, 0.f, 0.f, 0.f};

  if constexpr (DIRECT) {
    // -------- 1x1 conv: B-fragments loaded straight from global, no barriers
#pragma unroll
    for (int ch = 0; ch < NCH; ++ch) {
      const int k0 = ch * 32;
      h8v afr[MFR];
#pragma unroll
      for (int mf = 0; mf < MFR; ++mf)
        afr[mf] = *(const h8v*)(wp + ((size_t)(co0 + mf * 16 + ln)) * KP + k0 + lg * 8);
#pragma unroll
      for (int pf = 0; pf < WPIX; ++pf) {
        const int pix = r0 * IMGO + wid * (WPIX * 16) + pf * 16 + ln;
        h8v bfr = (h8v){0, 0, 0, 0, 0, 0, 0, 0};
        if (DUAL) {
          bfr = (ch == 0)
              ? *(const h8v*)(src0 + (((size_t)b * NPIXI + pix) * 32 + lg * 8))
              : *(const h8v*)(src1 + (((size_t)n * NPIXI + pix) * 32 + lg * 8));
        } else {
          const int gci = k0 + lg * 8;
          if (gci < G)
            bfr = *(const h8v*)(src1 + (((size_t)n * NPIXI + pix) * G + gci));
        }
#pragma unroll
        for (int mf = 0; mf < MFR; ++mf)
          acc[mf][pf] = __builtin_amdgcn_mfma_f32_16x16x32_f16(afr[mf], bfr, acc[mf][pf], 0, 0, 0);
      }
    }
  } else {
    // -------- LDS-staged path with 2-phase pipeline
    s8v rbuf[CPT];
    // stage_load: coalesced (consecutive lanes -> consecutive 16B chunks of a pixel row)
    auto stage_load = [&](int k0) {
#pragma unroll
      for (int j = 0; j < CPT; ++j) {
        const int cidx = tid + j * 256;
        s8v v = (s8v){0, 0, 0, 0, 0, 0, 0, 0};
        if (cidx < NCHUNK) {
          const int s = cidx >> 2, p = cidx & 3;
          const int rs = s / TC, cs = s - rs * TC;
          int ir, ic;
          if (GEOM == 1) { ir = 2 * r0 - 1 + rs; ic = (cs < 32) ? 2 * cs : 2 * (cs - 32) - 1; }
          else           { ir = r0 - 1 + rs;     ic = cs - 1; }
          const int gci = k0 + p * 8;
          if (((unsigned)ir < (unsigned)IMGI) && ((unsigned)ic < (unsigned)IMGI)) {
            const int ipix = ir * IMGI + ic;
            if (DUAL) {
              if (gci < 32)
                v = *(const s8v*)(src0 + (((size_t)b * NPIXI + ipix) * 32 + gci));
              else
                v = *(const s8v*)(src1 + (((size_t)n * NPIXI + ipix) * 32 + (gci - 32)));
            } else if (gci < G) {
              v = *(const s8v*)(src1 + (((size_t)n * NPIXI + ipix) * G + gci));
            }
          }
        }
        rbuf[j] = v;
      }
    };
    auto stage_write = [&]() {
#pragma unroll
      for (int j = 0; j < CPT; ++j) {
        const int cidx = tid + j * 256;
        if (cidx < NCHUNK) {
          const int s = cidx >> 2, p = cidx & 3;
          *(s8v*)(&lds[(size_t)(p * PSTR + s) * 8]) = rbuf[j];
        }
      }
    };

    stage_load(0);
#pragma unroll
    for (int ch = 0; ch < NCH; ++ch) {
      if (ch > 0) __syncthreads();
      stage_write();
      __syncthreads();
      if (ch + 1 < NCH) stage_load((ch + 1) * 32);
      const int k0 = ch * 32;
#pragma unroll
      for (int t = 0; t < TAPS; ++t) {
        int dh, dw, wt, kh = 0, kw = 0;
        if (GEOM == 2) {
          dh = qq + (t >> 1) - 1; dw = pp + (t & 1) - 1;
          wt = (qq + 2 * (t >> 1)) * 4 + (pp + 2 * (t & 1));
        } else { kh = t / 3; kw = t % 3; dh = kh - 1; dw = kw - 1; wt = t; }
        h8v afr[MFR];
#pragma unroll
        for (int mf = 0; mf < MFR; ++mf)
          afr[mf] = *(const h8v*)(wp + ((size_t)(wt * COP + co0 + mf * 16 + ln)) * KP + k0 + lg * 8);
#pragma unroll
        for (int pf = 0; pf < WPIX; ++pf) {
          const int pl = wid * (WPIX * 16) + pf * 16 + ln;
          const int rL = pl / IMGO, c = pl - rL * IMGO;
          int slot;
          if (GEOM == 1) slot = (2 * rL + kh) * 65 + ((kw == 1) ? c : (32 + c + (kw >> 1)));
          else           slot = (rL + dh + 1) * TC + (c + dw + 1);
          const h8v bfr = *(const h8v*)(&lds[(size_t)(lg * PSTR + slot) * 8]);
#pragma unroll
          for (int mf = 0; mf < MFR; ++mf)
            acc[mf][pf] = __builtin_amdgcn_mfma_f32_16x16x32_f16(afr[mf], bfr, acc[mf][pf], 0, 0, 0);
        }
      }
    }
  }

  const float di = (float)(ij / 9) - 4.f, dj = (float)(ij % 9) - 4.f;

  if constexpr (EPI == 3) {
    if (lg == 0) {
#pragma unroll
      for (int pf = 0; pf < WPIX; ++pf) {
        const int pl = wid * (WPIX * 16) + pf * 16 + ln;
        const int rL = pl / IMGO, c = pl - rL * IMGO;
        const int opix = (r0 + rL) * IMGO + c;
        outF[((size_t)(b * 113 + ij)) * 4096 + opix] = acc[0][pf][0] + bias[0];
      }
    }
    return;
  } else {
#pragma unroll
    for (int mf = 0; mf < MFR; ++mf) {
#pragma unroll
      for (int pf = 0; pf < WPIX; ++pf) {
        const int pl = wid * (WPIX * 16) + pf * 16 + ln;
        const int rL = pl / IMGO, c = pl - rL * IMGO;
        int opix;
        if constexpr (GEOM == 2) opix = (2 * (r0 + rL) + qq) * 64 + 2 * c + pp;
        else opix = (r0 + rL) * IMGO + c;
        if constexpr (DELTA && EPI == 0) {
          const int oh = r0 + rL;
          const int rc = (oh == 0) ? 0 : ((oh == IMGO - 1) ? 2 : 1);
          const int cc = (c == 0) ? 0 : ((c == IMGO - 1) ? 2 : 1);
#pragma unroll
          for (int rg = 0; rg < 4; ++rg) {
            const int co = co0 + mf * 16 + lg * 4 + rg;
            acc[mf][pf][rg] += di * dtab[(co * 9 + rc * 3 + cc) * 2 + 0] +
                               dj * dtab[(co * 9 + rc * 3 + cc) * 2 + 1];
          }
        }
        if constexpr (DELTA && EPI == 1) {
#pragma unroll
          for (int rg = 0; rg < 4; ++rg) {
            const int co = co0 + mf * 16 + lg * 4 + rg;
            acc[mf][pf][rg] += di * dtab[co * 2] + dj * dtab[co * 2 + 1];
          }
        }
        if constexpr (EPI == 1 || EPI == 2) {
          const float4 bv = *(const float4*)(bias + co0 + mf * 16 + lg * 4);
          acc[mf][pf][0] += bv.x; acc[mf][pf][1] += bv.y;
          acc[mf][pf][2] += bv.z; acc[mf][pf][3] += bv.w;
          if constexpr (EPI == 1) {
#pragma unroll
            for (int rg = 0; rg < 4; ++rg) acc[mf][pf][rg] = fmaxf(acc[mf][pf][rg], 0.f);
          }
        }
        ushort4 st;
        st.x = f2h_bits(acc[mf][pf][0]); st.y = f2h_bits(acc[mf][pf][1]);
        st.z = f2h_bits(acc[mf][pf][2]); st.w = f2h_bits(acc[mf][pf][3]);
        *reinterpret_cast<ushort4*>(outB + ((size_t)n * NPIXO + opix) * COB + co0 + mf * 16 + lg * 4) = st;
      }
    }
    if constexpr (EPI == 0) {
      __syncthreads();          // all waves done reading LDS before scratch reuse
      float* sl = (float*)lds;
#pragma unroll
      for (int mf = 0; mf < MFR; ++mf) {
#pragma unroll
        for (int rg = 0; rg < 4; ++rg) {
          float s = 0.f, q2 = 0.f;
#pragma unroll
          for (int pf = 0; pf < WPIX; ++pf) {
            const float v = acc[mf][pf][rg];
            s += v; q2 += v * v;
          }
#pragma unroll
          for (int o = 1; o < 16; o <<= 1) { s += __shfl_xor(s, o); q2 += __shfl_xor(q2, o); }
          if (ln == 0) {
            const int cl = mf * 16 + lg * 4 + rg;
            sl[(wid * MFR * 16 + cl) * 2 + 0] = s;
            sl[(wid * MFR * 16 + cl) * 2 + 1] = q2;
          }
        }
      }
      __syncthreads();
      for (int i = tid; i < MFR * 16 * 2; i += 256) {
        const int cl = i >> 1, stt = i & 1;
        float tot = 0.f;
#pragma unroll
        for (int w = 0; w < 4; ++w) tot += sl[(w * MFR * 16 + cl) * 2 + stt];
        atomicAdd(&statL[2 * (co0 + cl) + stt], tot);
      }
    }
  }
}

// ---------------------------------------------------------------- BN finalize
__global__ void bnfin_kernel(float* __restrict__ statL, const float* __restrict__ g,
                             const float* __restrict__ bt, int C, float invCnt) {
  const int c = threadIdx.x;
  if (c < C) {
    const float m = statL[2 * c] * invCnt;
    const float var = statL[2 * c + 1] * invCnt - m * m;
    const float sc = g[c] * rsqrtf(var + 1e-5f);
    statL[256 + c] = sc;
    statL[384 + c] = bt[c] - m * sc;
  }
}

// ---------------------------------------------------------------- in-place BN+ReLU
template <int G8>
__global__ __launch_bounds__(256) void norm_ip(hf* __restrict__ x,
                                               const float* __restrict__ statL, long nch) {
  for (long i = (long)blockIdx.x * 256 + threadIdx.x; i < nch; i += (long)gridDim.x * 256) {
    const int ci8 = (int)(i % G8);
    s8v v = *(s8v*)(x + i * 8);
    const f32x4 scA = *(const f32x4*)(statL + 256 + ci8 * 8);
    const f32x4 scB = *(const f32x4*)(statL + 256 + ci8 * 8 + 4);
    const f32x4 shA = *(const f32x4*)(statL + 384 + ci8 * 8);
    const f32x4 shB = *(const f32x4*)(statL + 384 + ci8 * 8 + 4);
    s8v o;
#pragma unroll
    for (int j = 0; j < 8; ++j) {
      const float sc = (j < 4) ? scA[j] : scB[j - 4];
      const float sh = (j < 4) ? shA[j] : shB[j - 4];
      const float f = fmaxf(h2f_bits((unsigned short)v[j]) * sc + sh, 0.f);
      o[j] = (short)f2h_bits(f);
    }
    *(s8v*)(x + i * 8) = o;
  }
}

// ---------------------------------------------------------------- DAP softmax
__global__ __launch_bounds__(64) void softmax_kernel(
    const float* __restrict__ outp, const float* __restrict__ dapw, float* __restrict__ score) {
  __shared__ float cb[64 * 81];
  __shared__ float sb[64 * 81];
  const int t = threadIdx.x;
  const int gid = blockIdx.x * 64 + t;
  const int b = gid >> 12, hw = gid & 4095;
  for (int d = 0; d < 81; ++d)
    cb[t * 81 + d] = outp[((size_t)(b * 113 + d)) * 4096 + hw];
  float smax = -1e30f;
  for (int o = 0; o < 81; ++o) {
    float s = 0.f;
    const float* dr = dapw + o * 81;
    for (int d = 0; d < 81; ++d) s += dr[d] * cb[t * 81 + d];
    sb[t * 81 + o] = s;
    smax = fmaxf(smax, s);
  }
  float sum = 0.f;
  for (int o = 0; o < 81; ++o) {
    const float e = __expf(sb[t * 81 + o] - smax);
    sb[t * 81 + o] = e;
    sum += e;
  }
  const float inv = 1.f / sum;
  for (int o = 0; o < 81; ++o)
    score[((size_t)(b * 81 + o)) * 4096 + hw] = sb[t * 81 + o] * inv;
}

// ---------------------------------------------------------------- emb reduce
__global__ __launch_bounds__(256) void emb_kernel(
    const float* __restrict__ score, const hf* __restrict__ e3, float* __restrict__ outp) {
  const int idx = blockIdx.x * 256 + threadIdx.x;  // 2*32*4096
  const int b = idx >> 17, r = idx & 131071, m = r >> 12, hw = r & 4095;
  float acc = 0.f;
  for (int d = 0; d < 81; ++d) {
    const float sc = score[((size_t)(b * 81 + d)) * 4096 + hw];
    acc += sc * (float)e3[(((size_t)(b * 81 + d)) * 4096 + hw) * 32 + m];
  }
  outp[((size_t)(b * 113 + 81 + m)) * 4096 + hw] = acc;
}

// ======================================================================
extern "C" void kernel_launch(void* const* d_in, const int* in_sizes, int n_in,
                              void* d_out, int out_size, void* d_ws, size_t ws_size,
                              hipStream_t stream) {
  const float* f1     = (const float*)d_in[0];
  const float* f2     = (const float*)d_in[1];
  const float* coords = (const float*)d_in[2];
  const float* w1     = (const float*)d_in[3];
  const float* g1     = (const float*)d_in[4];
  const float* bb1    = (const float*)d_in[5];
  const float* w2     = (const float*)d_in[6];
  const float* g2     = (const float*)d_in[7];
  const float* bb2    = (const float*)d_in[8];
  const float* w3     = (const float*)d_in[9];
  const float* g3     = (const float*)d_in[10];
  const float* bb3    = (const float*)d_in[11];
  const float* w4     = (const float*)d_in[12];
  const float* g4     = (const float*)d_in[13];
  const float* bb4    = (const float*)d_in[14];
  const float* wdcv   = (const float*)d_in[15];
  const float* gd     = (const float*)d_in[16];
  const float* bbd    = (const float*)d_in[17];
  const float* w5     = (const float*)d_in[18];
  const float* b5     = (const float*)d_in[19];
  const float* e1w    = (const float*)d_in[20];
  const float* e1bi   = (const float*)d_in[21];
  const float* e2w    = (const float*)d_in[22];
  const float* e2bi   = (const float*)d_in[23];
  const float* e3w    = (const float*)d_in[24];
  const float* e3bi   = (const float*)d_in[25];
  const float* dapw   = (const float*)d_in[26];
  float* out = (float*)d_out;
  char* ws = (char*)d_ws;

  hf* sA  = (hf*)(ws + OFF_SA);
  hf* f2s = (hf*)(ws + OFF_F2S);
  hf* be1 = (hf*)(ws + OFF_E1);
  hf* be2 = (hf*)(ws + OFF_E2);
  hf* be3 = (hf*)(ws + OFF_E3);
  hf* x1  = (hf*)(ws + OFF_X1);
  hf* x2  = (hf*)(ws + OFF_X2);
  hf* x3  = (hf*)(ws + OFF_X3);
  hf* x4  = (hf*)(ws + OFF_X4);
  hf* xd  = (hf*)(ws + OFF_XD);
  float* score = (float*)(ws + OFF_SCORE);
  float* stats = (float*)(ws + OFF_STATS);
  hf* wc1 = (hf*)(ws + OFF_WC1);
  hf* wc2 = (hf*)(ws + OFF_WC2);
  hf* wc3 = (hf*)(ws + OFF_WC3);
  hf* wc4 = (hf*)(ws + OFF_WC4);
  hf* wdc = (hf*)(ws + OFF_WDC);
  hf* wc5 = (hf*)(ws + OFF_WC5);
  hf* we1 = (hf*)(ws + OFF_WE1);
  hf* we2 = (hf*)(ws + OFF_WE2);
  hf* we3 = (hf*)(ws + OFF_WE3);
  float* dt1 = (float*)(ws + OFF_DT1);
  float* dtE = (float*)(ws + OFF_DTE);
  float* f2clf = (float*)(ws + OFF_F2CLF);

  hipMemsetAsync(stats, 0, 2560 * sizeof(float), stream);

  // weight prepacks
  prepack<<<216, 256, 0, stream>>>(w1,   wc1, 96, 96, 64, 66, 64, 9);
  prepack<<<432, 256, 0, stream>>>(w2,   wc2, 128, 128, 96, 96, 96, 9);
  prepack<<<576, 256, 0, stream>>>(w3,   wc3, 128, 128, 128, 128, 128, 9);
  prepack<<<288, 256, 0, stream>>>(w4,   wc4, 64, 64, 128, 128, 128, 9);
  prepack<<<128, 256, 0, stream>>>(wdcv, wdc, 32, 32, 64, 64, 64, 16);
  prepack<<<18,  256, 0, stream>>>(w5,   wc5, 1, 16, 32, 32, 32, 9);
  prepack<<<12,  256, 0, stream>>>(e1w,  we1, 48, 48, 64, 66, 64, 1);
  prepack<<<16,  256, 0, stream>>>(e2w,  we2, 64, 64, 48, 48, 64, 1);
  prepack<<<8,   256, 0, stream>>>(e3w,  we3, 32, 32, 64, 64, 64, 1);
  dtab1_kernel<<<7, 256, 0, stream>>>(w1, dt1);
  dtabE_kernel<<<1, 96, 0, stream>>>(e1w, dtE);

  // inputs
  packf1<<<32, 256, 0, stream>>>(f1, sA);
  packf2f32<<<32, 256, 0, stream>>>(f2, f2clf);
  sample2<<<2592, 256, 0, stream>>>(f2clf, coords, f2s);

  // embedding branch (DIRECT 1x1 convs)
  mconv<3, 1, true, 32, 64, 48, 48, 3, 64, 64, 4, 4, true>
      <<<dim3(16, 1, 162), 256, 0, stream>>>(f2s, sA, we1, e1bi, dtE, nullptr, be1, nullptr);
  mconv<3, 1, false, 48, 64, 64, 64, 4, 64, 64, 4, 4, false>
      <<<dim3(16, 1, 162), 256, 0, stream>>>(be1, nullptr, we2, e2bi, nullptr, nullptr, be2, nullptr);
  mconv<3, 2, false, 64, 64, 32, 32, 2, 64, 64, 4, 4, false>
      <<<dim3(16, 1, 162), 256, 0, stream>>>(be2, nullptr, we3, e3bi, nullptr, nullptr, be3, nullptr);

  // matching branch
  mconv<0, 0, true, 32, 64, 96, 96, 3, 64, 64, 2, 2, true>
      <<<dim3(32, 2, 162), 256, 0, stream>>>(f2s, sA, wc1, nullptr, dt1, stats + 0, x1, nullptr);
  bnfin_kernel<<<1, 128, 0, stream>>>(stats + 0, g1, bb1, 96, 1.f / 663552.f);
  norm_ip<12><<<2048, 256, 0, stream>>>(x1, stats + 0, 7962624L);

  mconv<1, 0, false, 96, 96, 128, 128, 4, 32, 64, 2, 1, false>
      <<<dim3(16, 2, 162), 256, 0, stream>>>(x1, nullptr, wc2, nullptr, nullptr, stats + 512, x2, nullptr);
  bnfin_kernel<<<1, 128, 0, stream>>>(stats + 512, g2, bb2, 128, 1.f / 165888.f);
  norm_ip<16><<<2048, 256, 0, stream>>>(x2, stats + 512, 2654208L);

  mconv<0, 0, false, 128, 128, 128, 128, 4, 32, 32, 4, 2, false>
      <<<dim3(8, 2, 162), 256, 0, stream>>>(x2, nullptr, wc3, nullptr, nullptr, stats + 1024, x3, nullptr);
  bnfin_kernel<<<1, 128, 0, stream>>>(stats + 1024, g3, bb3, 128, 1.f / 165888.f);
  norm_ip<16><<<2048, 256, 0, stream>>>(x3, stats + 1024, 2654208L);

  mconv<0, 0, false, 128, 128, 64, 64, 4, 32, 32, 4, 2, false>
      <<<dim3(8, 1, 162), 256, 0, stream>>>(x3, nullptr, wc4, nullptr, nullptr, stats + 1536, x4, nullptr);
  bnfin_kernel<<<1, 128, 0, stream>>>(stats + 1536, g4, bb4, 64, 1.f / 165888.f);
  norm_ip<8><<<2048, 256, 0, stream>>>(x4, stats + 1536, 1327104L);

  mconv<2, 0, false, 64, 64, 32, 32, 2, 32, 32, 8, 4, false>
      <<<dim3(4, 4, 162), 256, 0, stream>>>(x4, nullptr, wdc, nullptr, nullptr, stats + 2048, xd, nullptr);
  bnfin_kernel<<<1, 128, 0, stream>>>(stats + 2048, gd, bbd, 32, 1.f / 663552.f);
  norm_ip<4><<<2048, 256, 0, stream>>>(xd, stats + 2048, 2654208L);

  mconv<0, 3, false, 32, 32, 16, 16, 1, 64, 64, 4, 4, false>
      <<<dim3(16, 1, 162), 256, 0, stream>>>(xd, nullptr, wc5, b5, nullptr, nullptr, nullptr, out);

  // DAP softmax + embedding reduction
  softmax_kernel<<<128, 64, 0, stream>>>(out, dapw, score);
  emb_kernel<<<1024, 256, 0, stream>>>(score, be3, out);

  (void)in_sizes; (void)n_in; (void)out_size; (void)ws_size;
}

// Round 9
// 1142.539 us; speedup vs baseline: 1.1499x; 1.1499x over previous
//
#include <hip/hip_runtime.h>
#include <hip/hip_bf16.h>

typedef _Float16 hf;
typedef short    s8v  __attribute__((ext_vector_type(8)));
typedef _Float16 h8v  __attribute__((ext_vector_type(8)));
typedef float    f32x4 __attribute__((ext_vector_type(4)));

#define DEVINL __device__ __forceinline__

DEVINL unsigned short f2h_bits(float f) { return __builtin_bit_cast(unsigned short, (hf)f); }
DEVINL float h2f_bits(unsigned short u) { return (float)__builtin_bit_cast(hf, u); }

// ---------------------------------------------------------------- arena
static constexpr size_t OFF_SA    = 0;           // f1 packed  [2][4096][32] hf
static constexpr size_t OFF_F2S   = 524288;      // f2 sampled [162][4096][32] hf
static constexpr size_t OFF_E1    = 42991616;    // e1out [162][4096][48]
static constexpr size_t OFF_E2    = 106692608;   // e2out [162][4096][64]
static constexpr size_t OFF_E3    = 42991616;    // e3out [162][4096][32] (reuse E1)
static constexpr size_t OFF_X1    = 85458944;    // x1 [162][4096][96]
static constexpr size_t OFF_X2    = 524288;      // x2 [162][1024][128]
static constexpr size_t OFF_X3    = 85458944;    // x3 [162][1024][128]
static constexpr size_t OFF_X4    = 524288;      // x4 [162][1024][64]
static constexpr size_t OFF_XD    = 127926272;   // xd [162][4096][32]
static constexpr size_t OFF_SCORE = 524288;      // f32 [2][81][4096]
static constexpr size_t OFF_STATS = 212860928;   // f32 2560
static constexpr size_t OFF_WC1   = 212871168;
static constexpr size_t OFF_WC2   = 212981760;
static constexpr size_t OFF_WC3   = 213202944;
static constexpr size_t OFF_WC4   = 213497856;
static constexpr size_t OFF_WDC   = 213645312;
static constexpr size_t OFF_WE1   = 213720064;
static constexpr size_t OFF_WE2   = 213726208;
static constexpr size_t OFF_WE3   = 213734400;
static constexpr size_t OFF_DT1   = 213738496;
static constexpr size_t OFF_DTE   = 213745408;
static constexpr size_t OFF_F2CLF = 213746048;   // f2 packed [2][4096][32] f32 (1 MB)

// ---------------------------------------------------------------- prepack
__global__ void prepack(const float* __restrict__ src, hf* __restrict__ dst,
                        int COr, int COP, int CINr, int CINsrc, int KP, int TAPS) {
  const int idx = blockIdx.x * 256 + threadIdx.x;
  const int total = TAPS * COP * KP;
  if (idx >= total) return;
  const int k = idx % KP;
  const int r = idx / KP;
  const int co = r % COP;
  const int t = r / COP;
  float v = 0.f;
  if (co < COr && k < CINr) v = src[((size_t)co * CINsrc + k) * TAPS + t];
  dst[idx] = (hf)v;
}

__global__ void dtab1_kernel(const float* __restrict__ w1, float* __restrict__ dtab) {
  const int idx = blockIdx.x * 256 + threadIdx.x;  // 96*9*2
  if (idx >= 96 * 9 * 2) return;
  const int c = idx & 1;
  const int r = idx >> 1;
  const int pat = r % 9;
  const int co = r / 9;
  const int rc = pat / 3, cc = pat % 3;
  const int kh0 = (rc == 0) ? 1 : 0, kh1 = (rc == 2) ? 1 : 2;
  const int kw0 = (cc == 0) ? 1 : 0, kw1 = (cc == 2) ? 1 : 2;
  float s = 0.f;
  for (int kh = kh0; kh <= kh1; ++kh)
    for (int kw = kw0; kw <= kw1; ++kw)
      s += w1[((size_t)(co * 66 + 64 + c) * 3 + kh) * 3 + kw];
  dtab[(co * 9 + pat) * 2 + c] = s;
}

__global__ void dtabE_kernel(const float* __restrict__ e1w, float* __restrict__ dtE) {
  const int co = threadIdx.x;
  if (co < 48) {
    dtE[co * 2 + 0] = e1w[co * 66 + 64];
    dtE[co * 2 + 1] = e1w[co * 66 + 65];
  }
}

// ---------------------------------------------------------------- input builders
__global__ __launch_bounds__(256) void packf1(const float* __restrict__ f1, hf* __restrict__ sA) {
  const int gid = blockIdx.x * 256 + threadIdx.x;  // 2*4096
  const int b = gid >> 12, pix = gid & 4095;
  unsigned words[16];
#pragma unroll
  for (int c = 0; c < 32; c += 2) {
    const float v0 = f1[((size_t)(b * 32 + c)) * 4096 + pix];
    const float v1 = f1[((size_t)(b * 32 + c + 1)) * 4096 + pix];
    words[c >> 1] = (unsigned)f2h_bits(v0) | ((unsigned)f2h_bits(v1) << 16);
  }
  uint4* dst = (uint4*)(sA + (size_t)gid * 32);
#pragma unroll
  for (int i = 0; i < 4; ++i)
    dst[i] = make_uint4(words[4 * i], words[4 * i + 1], words[4 * i + 2], words[4 * i + 3]);
}

__global__ __launch_bounds__(256) void packf2f32(const float* __restrict__ f2,
                                                 float* __restrict__ dst) {
  const int gid = blockIdx.x * 256 + threadIdx.x;  // 2*4096
  const int b = gid >> 12, pix = gid & 4095;
  float* op = dst + (size_t)gid * 32;
#pragma unroll
  for (int c = 0; c < 32; c += 4) {
    float4 v;
    v.x = f2[((size_t)(b * 32 + c + 0)) * 4096 + pix];
    v.y = f2[((size_t)(b * 32 + c + 1)) * 4096 + pix];
    v.z = f2[((size_t)(b * 32 + c + 2)) * 4096 + pix];
    v.w = f2[((size_t)(b * 32 + c + 3)) * 4096 + pix];
    *(float4*)(op + c) = v;
  }
}

__global__ __launch_bounds__(256) void sample2(const float* __restrict__ f2clf,
                                               const float* __restrict__ coords,
                                               hf* __restrict__ f2s) {
  const int gid = blockIdx.x * 256 + threadIdx.x;  // 162*4096
  const int n = gid >> 12, pix = gid & 4095;
  const int b = n / 81, ij = n - b * 81;
  const float di = (float)(ij / 9) - 4.f, dj = (float)(ij % 9) - 4.f;
  const float x = coords[((size_t)(b * 2 + 0)) * 4096 + pix] + di;
  const float y = coords[((size_t)(b * 2 + 1)) * 4096 + pix] + dj;
  const float x0f = floorf(x), y0f = floorf(y);
  const int x0 = (int)x0f, y0 = (int)y0f;
  const float wx1 = x - x0f, wx0 = 1.f - wx1;
  const float wy1 = y - y0f, wy0 = 1.f - wy1;
  const bool vx0 = (unsigned)x0 < 64u, vx1 = (unsigned)(x0 + 1) < 64u;
  const bool vy0 = (unsigned)y0 < 64u, vy1 = (unsigned)(y0 + 1) < 64u;
  const int x0c = min(max(x0, 0), 63), x1c = min(max(x0 + 1, 0), 63);
  const int y0c = min(max(y0, 0), 63), y1c = min(max(y0 + 1, 0), 63);
  const float w00 = (vy0 && vx0) ? wy0 * wx0 : 0.f;
  const float w01 = (vy0 && vx1) ? wy0 * wx1 : 0.f;
  const float w10 = (vy1 && vx0) ? wy1 * wx0 : 0.f;
  const float w11 = (vy1 && vx1) ? wy1 * wx1 : 0.f;
  const float* fb = f2clf + (size_t)b * 4096 * 32;
  const float* p00 = fb + (size_t)(y0c * 64 + x0c) * 32;
  const float* p01 = fb + (size_t)(y0c * 64 + x1c) * 32;
  const float* p10 = fb + (size_t)(y1c * 64 + x0c) * 32;
  const float* p11 = fb + (size_t)(y1c * 64 + x1c) * 32;
  unsigned words[16];
#pragma unroll
  for (int ch = 0; ch < 16; ++ch) {
    const float2 a  = *(const float2*)(p00 + ch * 2);
    const float2 bb = *(const float2*)(p01 + ch * 2);
    const float2 c  = *(const float2*)(p10 + ch * 2);
    const float2 d  = *(const float2*)(p11 + ch * 2);
    const float v0 = w00 * a.x + w01 * bb.x + w10 * c.x + w11 * d.x;
    const float v1 = w00 * a.y + w01 * bb.y + w10 * c.y + w11 * d.y;
    words[ch] = (unsigned)f2h_bits(v0) | ((unsigned)f2h_bits(v1) << 16);
  }
  uint4* dst = (uint4*)(f2s + (size_t)gid * 32);
#pragma unroll
  for (int i = 0; i < 4; ++i)
    dst[i] = make_uint4(words[4 * i], words[4 * i + 1], words[4 * i + 2], words[4 * i + 3]);
}

// ---------------------------------------------------------------- MFMA conv template
// GEOM: 0 = 3x3 s1 | 1 = 3x3 s2 (64->32) | 2 = deconv parity | 3 = 1x1 (DIRECT, no LDS)
// EPI : 0 = raw store + BN stats | 1 = bias+relu | 2 = bias
template <int GEOM, int EPI, bool DUAL, int G, int KP, int COP, int COB, int MFR,
          int IMGO, int IMGI, int PIXROWS, int WPIX, bool DELTA>
__global__ __launch_bounds__(256) void mconv(
    const hf* __restrict__ src1, const hf* __restrict__ src0,
    const hf* __restrict__ wp, const float* __restrict__ bias,
    const float* __restrict__ dtab, float* __restrict__ statL,
    hf* __restrict__ outB, float* __restrict__ outF) {
  constexpr bool DIRECT = (GEOM == 3);
  constexpr int TAPS  = (GEOM == 2) ? 4 : (GEOM == 3) ? 1 : 9;
  constexpr int TR    = (GEOM == 1) ? (2 * PIXROWS + 1) : (GEOM == 3) ? 1 : (PIXROWS + 2);
  constexpr int TC    = (GEOM == 1) ? 65 : (GEOM == 3) ? 1 : (IMGI + 2);
  constexpr int NSLOT = TR * TC;
  constexpr int PSTR  = NSLOT + 1;
  constexpr int NCH   = KP / 32;
  constexpr int NPIXI = IMGI * IMGI;
  constexpr int NPIXO = (GEOM == 2) ? 4096 : IMGO * IMGO;
  constexpr int NCHUNK = NSLOT * 4;
  constexpr int CPT   = (NCHUNK + 255) / 256;
  constexpr int LDSE  = DIRECT ? 64 : 4 * PSTR * 8;

  __shared__ __align__(16) hf lds[LDSE];

  const int tid = threadIdx.x;
  const int wid = tid >> 6, lane = tid & 63, lg = lane >> 4, ln = lane & 15;
  const int n = blockIdx.z, b = n / 81, ij = n - b * 81;
  const int r0 = blockIdx.x * PIXROWS;
  const int qq = (GEOM == 2) ? (int)(blockIdx.y >> 1) : 0;
  const int pp = (GEOM == 2) ? (int)(blockIdx.y & 1) : 0;
  const int co0 = (GEOM == 2) ? 0 : (int)blockIdx.y * (MFR * 16);

  f32x4 acc[MFR][WPIX];
#pragma unroll
  for (int mf = 0; mf < MFR; ++mf)
#pragma unroll
    for (int pf = 0; pf < WPIX; ++pf) acc[mf][pf] = (f32x4){0.f, 0.f, 0.f, 0.f};

  if constexpr (DIRECT) {
    // -------- 1x1 conv: B-fragments loaded straight from global, no barriers
#pragma unroll
    for (int ch = 0; ch < NCH; ++ch) {
      const int k0 = ch * 32;
      h8v afr[MFR];
#pragma unroll
      for (int mf = 0; mf < MFR; ++mf)
        afr[mf] = *(const h8v*)(wp + ((size_t)(co0 + mf * 16 + ln)) * KP + k0 + lg * 8);
#pragma unroll
      for (int pf = 0; pf < WPIX; ++pf) {
        const int pix = r0 * IMGO + wid * (WPIX * 16) + pf * 16 + ln;
        h8v bfr = (h8v){0, 0, 0, 0, 0, 0, 0, 0};
        if (DUAL) {
          bfr = (ch == 0)
              ? *(const h8v*)(src0 + (((size_t)b * NPIXI + pix) * 32 + lg * 8))
              : *(const h8v*)(src1 + (((size_t)n * NPIXI + pix) * 32 + lg * 8));
        } else {
          const int gci = k0 + lg * 8;
          if (gci < G)
            bfr = *(const h8v*)(src1 + (((size_t)n * NPIXI + pix) * G + gci));
        }
#pragma unroll
        for (int mf = 0; mf < MFR; ++mf)
          acc[mf][pf] = __builtin_amdgcn_mfma_f32_16x16x32_f16(afr[mf], bfr, acc[mf][pf], 0, 0, 0);
      }
    }
  } else {
    // -------- LDS-staged path with 2-phase pipeline
    s8v rbuf[CPT];
    auto stage_load = [&](int k0) {
#pragma unroll
      for (int j = 0; j < CPT; ++j) {
        const int cidx = tid + j * 256;
        s8v v = (s8v){0, 0, 0, 0, 0, 0, 0, 0};
        if (cidx < NCHUNK) {
          const int s = cidx >> 2, p = cidx & 3;
          const int rs = s / TC, cs = s - rs * TC;
          int ir, ic;
          if (GEOM == 1) { ir = 2 * r0 - 1 + rs; ic = (cs < 32) ? 2 * cs : 2 * (cs - 32) - 1; }
          else           { ir = r0 - 1 + rs;     ic = cs - 1; }
          const int gci = k0 + p * 8;
          if (((unsigned)ir < (unsigned)IMGI) && ((unsigned)ic < (unsigned)IMGI)) {
            const int ipix = ir * IMGI + ic;
            if (DUAL) {
              if (gci < 32)
                v = *(const s8v*)(src0 + (((size_t)b * NPIXI + ipix) * 32 + gci));
              else
                v = *(const s8v*)(src1 + (((size_t)n * NPIXI + ipix) * 32 + (gci - 32)));
            } else if (gci < G) {
              v = *(const s8v*)(src1 + (((size_t)n * NPIXI + ipix) * G + gci));
            }
          }
        }
        rbuf[j] = v;
      }
    };
    auto stage_write = [&]() {
#pragma unroll
      for (int j = 0; j < CPT; ++j) {
        const int cidx = tid + j * 256;
        if (cidx < NCHUNK) {
          const int s = cidx >> 2, p = cidx & 3;
          *(s8v*)(&lds[(size_t)(p * PSTR + s) * 8]) = rbuf[j];
        }
      }
    };

    stage_load(0);
#pragma unroll
    for (int ch = 0; ch < NCH; ++ch) {
      if (ch > 0) __syncthreads();
      stage_write();
      __syncthreads();
      if (ch + 1 < NCH) stage_load((ch + 1) * 32);
      const int k0 = ch * 32;
#pragma unroll
      for (int t = 0; t < TAPS; ++t) {
        int dh, dw, wt, kh = 0, kw = 0;
        if (GEOM == 2) {
          dh = qq + (t >> 1) - 1; dw = pp + (t & 1) - 1;
          wt = (qq + 2 * (t >> 1)) * 4 + (pp + 2 * (t & 1));
        } else { kh = t / 3; kw = t % 3; dh = kh - 1; dw = kw - 1; wt = t; }
        h8v afr[MFR];
#pragma unroll
        for (int mf = 0; mf < MFR; ++mf)
          afr[mf] = *(const h8v*)(wp + ((size_t)(wt * COP + co0 + mf * 16 + ln)) * KP + k0 + lg * 8);
#pragma unroll
        for (int pf = 0; pf < WPIX; ++pf) {
          const int pl = wid * (WPIX * 16) + pf * 16 + ln;
          const int rL = pl / IMGO, c = pl - rL * IMGO;
          int slot;
          if (GEOM == 1) slot = (2 * rL + kh) * 65 + ((kw == 1) ? c : (32 + c + (kw >> 1)));
          else           slot = (rL + dh + 1) * TC + (c + dw + 1);
          const h8v bfr = *(const h8v*)(&lds[(size_t)(lg * PSTR + slot) * 8]);
#pragma unroll
          for (int mf = 0; mf < MFR; ++mf)
            acc[mf][pf] = __builtin_amdgcn_mfma_f32_16x16x32_f16(afr[mf], bfr, acc[mf][pf], 0, 0, 0);
        }
      }
    }
  }

  const float di = (float)(ij / 9) - 4.f, dj = (float)(ij % 9) - 4.f;

  {
#pragma unroll
    for (int mf = 0; mf < MFR; ++mf) {
#pragma unroll
      for (int pf = 0; pf < WPIX; ++pf) {
        const int pl = wid * (WPIX * 16) + pf * 16 + ln;
        const int rL = pl / IMGO, c = pl - rL * IMGO;
        int opix;
        if constexpr (GEOM == 2) opix = (2 * (r0 + rL) + qq) * 64 + 2 * c + pp;
        else opix = (r0 + rL) * IMGO + c;
        if constexpr (DELTA && EPI == 0) {
          const int oh = r0 + rL;
          const int rc = (oh == 0) ? 0 : ((oh == IMGO - 1) ? 2 : 1);
          const int cc = (c == 0) ? 0 : ((c == IMGO - 1) ? 2 : 1);
#pragma unroll
          for (int rg = 0; rg < 4; ++rg) {
            const int co = co0 + mf * 16 + lg * 4 + rg;
            acc[mf][pf][rg] += di * dtab[(co * 9 + rc * 3 + cc) * 2 + 0] +
                               dj * dtab[(co * 9 + rc * 3 + cc) * 2 + 1];
          }
        }
        if constexpr (DELTA && EPI == 1) {
#pragma unroll
          for (int rg = 0; rg < 4; ++rg) {
            const int co = co0 + mf * 16 + lg * 4 + rg;
            acc[mf][pf][rg] += di * dtab[co * 2] + dj * dtab[co * 2 + 1];
          }
        }
        if constexpr (EPI == 1 || EPI == 2) {
          const float4 bv = *(const float4*)(bias + co0 + mf * 16 + lg * 4);
          acc[mf][pf][0] += bv.x; acc[mf][pf][1] += bv.y;
          acc[mf][pf][2] += bv.z; acc[mf][pf][3] += bv.w;
          if constexpr (EPI == 1) {
#pragma unroll
            for (int rg = 0; rg < 4; ++rg) acc[mf][pf][rg] = fmaxf(acc[mf][pf][rg], 0.f);
          }
        }
        ushort4 st;
        st.x = f2h_bits(acc[mf][pf][0]); st.y = f2h_bits(acc[mf][pf][1]);
        st.z = f2h_bits(acc[mf][pf][2]); st.w = f2h_bits(acc[mf][pf][3]);
        *reinterpret_cast<ushort4*>(outB + ((size_t)n * NPIXO + opix) * COB + co0 + mf * 16 + lg * 4) = st;
      }
    }
    if constexpr (EPI == 0) {
      __syncthreads();          // all waves done reading LDS before scratch reuse
      float* sl = (float*)lds;
#pragma unroll
      for (int mf = 0; mf < MFR; ++mf) {
#pragma unroll
        for (int rg = 0; rg < 4; ++rg) {
          float s = 0.f, q2 = 0.f;
#pragma unroll
          for (int pf = 0; pf < WPIX; ++pf) {
            const float v = acc[mf][pf][rg];
            s += v; q2 += v * v;
          }
#pragma unroll
          for (int o = 1; o < 16; o <<= 1) { s += __shfl_xor(s, o); q2 += __shfl_xor(q2, o); }
          if (ln == 0) {
            const int cl = mf * 16 + lg * 4 + rg;
            sl[(wid * MFR * 16 + cl) * 2 + 0] = s;
            sl[(wid * MFR * 16 + cl) * 2 + 1] = q2;
          }
        }
      }
      __syncthreads();
      for (int i = tid; i < MFR * 16 * 2; i += 256) {
        const int cl = i >> 1, stt = i & 1;
        float tot = 0.f;
#pragma unroll
        for (int w = 0; w < 4; ++w) tot += sl[(w * MFR * 16 + cl) * 2 + stt];
        atomicAdd(&statL[2 * (co0 + cl) + stt], tot);
      }
    }
  }
  (void)outF;
}

// ---------------------------------------------------------------- BN finalize
__global__ void bnfin_kernel(float* __restrict__ statL, const float* __restrict__ g,
                             const float* __restrict__ bt, int C, float invCnt) {
  const int c = threadIdx.x;
  if (c < C) {
    const float m = statL[2 * c] * invCnt;
    const float var = statL[2 * c + 1] * invCnt - m * m;
    const float sc = g[c] * rsqrtf(var + 1e-5f);
    statL[256 + c] = sc;
    statL[384 + c] = bt[c] - m * sc;
  }
}

// ---------------------------------------------------------------- in-place BN+ReLU
template <int G8>
__global__ __launch_bounds__(256) void norm_ip(hf* __restrict__ x,
                                               const float* __restrict__ statL, long nch) {
  for (long i = (long)blockIdx.x * 256 + threadIdx.x; i < nch; i += (long)gridDim.x * 256) {
    const int ci8 = (int)(i % G8);
    s8v v = *(s8v*)(x + i * 8);
    const f32x4 scA = *(const f32x4*)(statL + 256 + ci8 * 8);
    const f32x4 scB = *(const f32x4*)(statL + 256 + ci8 * 8 + 4);
    const f32x4 shA = *(const f32x4*)(statL + 384 + ci8 * 8);
    const f32x4 shB = *(const f32x4*)(statL + 384 + ci8 * 8 + 4);
    s8v o;
#pragma unroll
    for (int j = 0; j < 8; ++j) {
      const float sc = (j < 4) ? scA[j] : scB[j - 4];
      const float sh = (j < 4) ? shA[j] : shB[j - 4];
      const float f = fmaxf(h2f_bits((unsigned short)v[j]) * sc + sh, 0.f);
      o[j] = (short)f2h_bits(f);
    }
    *(s8v*)(x + i * 8) = o;
  }
}

// ---------------------------------------------------------------- conv5 (CO=1) on VALU
// reads NORMALIZED xd (post norm_ip), fp32 weights
__global__ __launch_bounds__(256) void conv5_kernel(
    const hf* __restrict__ xd, const float* __restrict__ w5, const float* __restrict__ b5,
    float* __restrict__ outp) {
  const int gid = blockIdx.x * 256 + threadIdx.x;  // 162*4096
  const int n = gid >> 12, pix = gid & 4095;
  const int b = n / 81, ij = n - b * 81;
  const int oh = pix >> 6, ow = pix & 63;
  float acc = b5[0];
#pragma unroll
  for (int kh = 0; kh < 3; ++kh) {
    const int ih = oh + kh - 1;
#pragma unroll
    for (int kw = 0; kw < 3; ++kw) {
      const int iw = ow + kw - 1;
      if (((unsigned)ih < 64u) && ((unsigned)iw < 64u)) {
        const hf* xp = xd + ((size_t)n * 4096 + ih * 64 + iw) * 32;
#pragma unroll
        for (int cq = 0; cq < 4; ++cq) {
          const h8v v = *(const h8v*)(xp + cq * 8);
#pragma unroll
          for (int j = 0; j < 8; ++j)
            acc += (float)v[j] * w5[(cq * 8 + j) * 9 + kh * 3 + kw];
        }
      }
    }
  }
  outp[((size_t)(b * 113 + ij)) * 4096 + pix] = acc;
}

// ---------------------------------------------------------------- DAP softmax
__global__ __launch_bounds__(64) void softmax_kernel(
    const float* __restrict__ outp, const float* __restrict__ dapw, float* __restrict__ score) {
  __shared__ float cb[64 * 81];
  __shared__ float sb[64 * 81];
  const int t = threadIdx.x;
  const int gid = blockIdx.x * 64 + t;
  const int b = gid >> 12, hw = gid & 4095;
  for (int d = 0; d < 81; ++d)
    cb[t * 81 + d] = outp[((size_t)(b * 113 + d)) * 4096 + hw];
  float smax = -1e30f;
  for (int o = 0; o < 81; ++o) {
    float s = 0.f;
    const float* dr = dapw + o * 81;
    for (int d = 0; d < 81; ++d) s += dr[d] * cb[t * 81 + d];
    sb[t * 81 + o] = s;
    smax = fmaxf(smax, s);
  }
  float sum = 0.f;
  for (int o = 0; o < 81; ++o) {
    const float e = __expf(sb[t * 81 + o] - smax);
    sb[t * 81 + o] = e;
    sum += e;
  }
  const float inv = 1.f / sum;
  for (int o = 0; o < 81; ++o)
    score[((size_t)(b * 81 + o)) * 4096 + hw] = sb[t * 81 + o] * inv;
}

// ---------------------------------------------------------------- emb reduce
__global__ __launch_bounds__(256) void emb_kernel(
    const float* __restrict__ score, const hf* __restrict__ e3, float* __restrict__ outp) {
  const int idx = blockIdx.x * 256 + threadIdx.x;  // 2*32*4096
  const int b = idx >> 17, r = idx & 131071, m = r >> 12, hw = r & 4095;
  float acc = 0.f;
  for (int d = 0; d < 81; ++d) {
    const float sc = score[((size_t)(b * 81 + d)) * 4096 + hw];
    acc += sc * (float)e3[(((size_t)(b * 81 + d)) * 4096 + hw) * 32 + m];
  }
  outp[((size_t)(b * 113 + 81 + m)) * 4096 + hw] = acc;
}

// ======================================================================
extern "C" void kernel_launch(void* const* d_in, const int* in_sizes, int n_in,
                              void* d_out, int out_size, void* d_ws, size_t ws_size,
                              hipStream_t stream) {
  const float* f1     = (const float*)d_in[0];
  const float* f2     = (const float*)d_in[1];
  const float* coords = (const float*)d_in[2];
  const float* w1     = (const float*)d_in[3];
  const float* g1     = (const float*)d_in[4];
  const float* bb1    = (const float*)d_in[5];
  const float* w2     = (const float*)d_in[6];
  const float* g2     = (const float*)d_in[7];
  const float* bb2    = (const float*)d_in[8];
  const float* w3     = (const float*)d_in[9];
  const float* g3     = (const float*)d_in[10];
  const float* bb3    = (const float*)d_in[11];
  const float* w4     = (const float*)d_in[12];
  const float* g4     = (const float*)d_in[13];
  const float* bb4    = (const float*)d_in[14];
  const float* wdcv   = (const float*)d_in[15];
  const float* gd     = (const float*)d_in[16];
  const float* bbd    = (const float*)d_in[17];
  const float* w5     = (const float*)d_in[18];
  const float* b5     = (const float*)d_in[19];
  const float* e1w    = (const float*)d_in[20];
  const float* e1bi   = (const float*)d_in[21];
  const float* e2w    = (const float*)d_in[22];
  const float* e2bi   = (const float*)d_in[23];
  const float* e3w    = (const float*)d_in[24];
  const float* e3bi   = (const float*)d_in[25];
  const float* dapw   = (const float*)d_in[26];
  float* out = (float*)d_out;
  char* ws = (char*)d_ws;

  hf* sA  = (hf*)(ws + OFF_SA);
  hf* f2s = (hf*)(ws + OFF_F2S);
  hf* be1 = (hf*)(ws + OFF_E1);
  hf* be2 = (hf*)(ws + OFF_E2);
  hf* be3 = (hf*)(ws + OFF_E3);
  hf* x1  = (hf*)(ws + OFF_X1);
  hf* x2  = (hf*)(ws + OFF_X2);
  hf* x3  = (hf*)(ws + OFF_X3);
  hf* x4  = (hf*)(ws + OFF_X4);
  hf* xd  = (hf*)(ws + OFF_XD);
  float* score = (float*)(ws + OFF_SCORE);
  float* stats = (float*)(ws + OFF_STATS);
  hf* wc1 = (hf*)(ws + OFF_WC1);
  hf* wc2 = (hf*)(ws + OFF_WC2);
  hf* wc3 = (hf*)(ws + OFF_WC3);
  hf* wc4 = (hf*)(ws + OFF_WC4);
  hf* wdc = (hf*)(ws + OFF_WDC);
  hf* we1 = (hf*)(ws + OFF_WE1);
  hf* we2 = (hf*)(ws + OFF_WE2);
  hf* we3 = (hf*)(ws + OFF_WE3);
  float* dt1 = (float*)(ws + OFF_DT1);
  float* dtE = (float*)(ws + OFF_DTE);
  float* f2clf = (float*)(ws + OFF_F2CLF);

  hipMemsetAsync(stats, 0, 2560 * sizeof(float), stream);

  // weight prepacks
  prepack<<<216, 256, 0, stream>>>(w1,   wc1, 96, 96, 64, 66, 64, 9);
  prepack<<<432, 256, 0, stream>>>(w2,   wc2, 128, 128, 96, 96, 96, 9);
  prepack<<<576, 256, 0, stream>>>(w3,   wc3, 128, 128, 128, 128, 128, 9);
  prepack<<<288, 256, 0, stream>>>(w4,   wc4, 64, 64, 128, 128, 128, 9);
  prepack<<<128, 256, 0, stream>>>(wdcv, wdc, 32, 32, 64, 64, 64, 16);
  prepack<<<12,  256, 0, stream>>>(e1w,  we1, 48, 48, 64, 66, 64, 1);
  prepack<<<16,  256, 0, stream>>>(e2w,  we2, 64, 64, 48, 48, 64, 1);
  prepack<<<8,   256, 0, stream>>>(e3w,  we3, 32, 32, 64, 64, 64, 1);
  dtab1_kernel<<<7, 256, 0, stream>>>(w1, dt1);
  dtabE_kernel<<<1, 96, 0, stream>>>(e1w, dtE);

  // inputs (f2 interpolated in fp32)
  packf1<<<32, 256, 0, stream>>>(f1, sA);
  packf2f32<<<32, 256, 0, stream>>>(f2, f2clf);
  sample2<<<2592, 256, 0, stream>>>(f2clf, coords, f2s);

  // embedding branch (DIRECT 1x1 convs)
  mconv<3, 1, true, 32, 64, 48, 48, 3, 64, 64, 4, 4, true>
      <<<dim3(16, 1, 162), 256, 0, stream>>>(f2s, sA, we1, e1bi, dtE, nullptr, be1, nullptr);
  mconv<3, 1, false, 48, 64, 64, 64, 4, 64, 64, 4, 4, false>
      <<<dim3(16, 1, 162), 256, 0, stream>>>(be1, nullptr, we2, e2bi, nullptr, nullptr, be2, nullptr);
  mconv<3, 2, false, 64, 64, 32, 32, 2, 64, 64, 4, 4, false>
      <<<dim3(16, 1, 162), 256, 0, stream>>>(be2, nullptr, we3, e3bi, nullptr, nullptr, be3, nullptr);

  // matching branch (conv1 retiled to PIXROWS=4/WPIX=4)
  mconv<0, 0, true, 32, 64, 96, 96, 3, 64, 64, 4, 4, true>
      <<<dim3(16, 2, 162), 256, 0, stream>>>(f2s, sA, wc1, nullptr, dt1, stats + 0, x1, nullptr);
  bnfin_kernel<<<1, 128, 0, stream>>>(stats + 0, g1, bb1, 96, 1.f / 663552.f);
  norm_ip<12><<<2048, 256, 0, stream>>>(x1, stats + 0, 7962624L);

  // conv2 retiled to PIXROWS=4/WPIX=2
  mconv<1, 0, false, 96, 96, 128, 128, 4, 32, 64, 4, 2, false>
      <<<dim3(8, 2, 162), 256, 0, stream>>>(x1, nullptr, wc2, nullptr, nullptr, stats + 512, x2, nullptr);
  bnfin_kernel<<<1, 128, 0, stream>>>(stats + 512, g2, bb2, 128, 1.f / 165888.f);
  norm_ip<16><<<2048, 256, 0, stream>>>(x2, stats + 512, 2654208L);

  mconv<0, 0, false, 128, 128, 128, 128, 4, 32, 32, 4, 2, false>
      <<<dim3(8, 2, 162), 256, 0, stream>>>(x2, nullptr, wc3, nullptr, nullptr, stats + 1024, x3, nullptr);
  bnfin_kernel<<<1, 128, 0, stream>>>(stats + 1024, g3, bb3, 128, 1.f / 165888.f);
  norm_ip<16><<<2048, 256, 0, stream>>>(x3, stats + 1024, 2654208L);

  mconv<0, 0, false, 128, 128, 64, 64, 4, 32, 32, 4, 2, false>
      <<<dim3(8, 1, 162), 256, 0, stream>>>(x3, nullptr, wc4, nullptr, nullptr, stats + 1536, x4, nullptr);
  bnfin_kernel<<<1, 128, 0, stream>>>(stats + 1536, g4, bb4, 64, 1.f / 165888.f);
  norm_ip<8><<<2048, 256, 0, stream>>>(x4, stats + 1536, 1327104L);

  mconv<2, 0, false, 64, 64, 32, 32, 2, 32, 32, 8, 4, false>
      <<<dim3(4, 4, 162), 256, 0, stream>>>(x4, nullptr, wdc, nullptr, nullptr, stats + 2048, xd, nullptr);
  bnfin_kernel<<<1, 128, 0, stream>>>(stats + 2048, gd, bbd, 32, 1.f / 663552.f);
  norm_ip<4><<<2048, 256, 0, stream>>>(xd, stats + 2048, 2654208L);

  // conv5 on VALU (reads normalized xd, fp32 weights) -> cost planes of out
  conv5_kernel<<<2592, 256, 0, stream>>>(xd, w5, b5, out);

  // DAP softmax + embedding reduction
  softmax_kernel<<<128, 64, 0, stream>>>(out, dapw, score);
  emb_kernel<<<1024, 256, 0, stream>>>(score, be3, out);

  (void)in_sizes; (void)n_in; (void)out_size; (void)ws_size;
}

// Round 11
// 1041.562 us; speedup vs baseline: 1.2614x; 1.0969x over previous
//
#include <hip/hip_runtime.h>
#include <hip/hip_bf16.h>

typedef _Float16 hf;
typedef short    s8v  __attribute__((ext_vector_type(8)));
typedef _Float16 h8v  __attribute__((ext_vector_type(8)));
typedef float    f32x4 __attribute__((ext_vector_type(4)));

#define DEVINL __device__ __forceinline__

DEVINL unsigned short f2h_bits(float f) { return __builtin_bit_cast(unsigned short, (hf)f); }
DEVINL float h2f_bits(unsigned short u) { return (float)__builtin_bit_cast(hf, u); }

// ---------------------------------------------------------------- arena
static constexpr size_t OFF_SA    = 0;           // f1 packed  [2][4096][32] hf
static constexpr size_t OFF_F2S   = 524288;      // f2 sampled [162][4096][32] hf
static constexpr size_t OFF_E1    = 42991616;    // e1out [162][4096][48]
static constexpr size_t OFF_E2    = 106692608;   // e2out [162][4096][64]
static constexpr size_t OFF_E3    = 42991616;    // e3out [162][4096][32] (reuse E1)
static constexpr size_t OFF_X1    = 85458944;    // x1 [162][4096][96]
static constexpr size_t OFF_X2    = 524288;      // x2 [162][1024][128]
static constexpr size_t OFF_X3    = 85458944;    // x3 [162][1024][128]
static constexpr size_t OFF_X4    = 524288;      // x4 [162][1024][64]
static constexpr size_t OFF_XD    = 127926272;   // xd [162][4096][32]
static constexpr size_t OFF_SCORE = 524288;      // f32 [2][81][4096]
static constexpr size_t OFF_STATS = 212860928;   // f32 2560
static constexpr size_t OFF_WC1   = 212871168;
static constexpr size_t OFF_WC2   = 212981760;
static constexpr size_t OFF_WC3   = 213202944;
static constexpr size_t OFF_WC4   = 213497856;
static constexpr size_t OFF_WDC   = 213645312;
static constexpr size_t OFF_WE1   = 213720064;
static constexpr size_t OFF_WE2   = 213726208;
static constexpr size_t OFF_WE3   = 213734400;
static constexpr size_t OFF_DT1   = 213738496;
static constexpr size_t OFF_DTE   = 213745408;
static constexpr size_t OFF_F2CLF = 213746048;   // f2 packed [2][4096][32] f32 (1 MB)

// ---------------------------------------------------------------- prepack
__global__ void prepack(const float* __restrict__ src, hf* __restrict__ dst,
                        int COr, int COP, int CINr, int CINsrc, int KP, int TAPS) {
  const int idx = blockIdx.x * 256 + threadIdx.x;
  const int total = TAPS * COP * KP;
  if (idx >= total) return;
  const int k = idx % KP;
  const int r = idx / KP;
  const int co = r % COP;
  const int t = r / COP;
  float v = 0.f;
  if (co < COr && k < CINr) v = src[((size_t)co * CINsrc + k) * TAPS + t];
  dst[idx] = (hf)v;
}

// dense layout: dst[t][ks][co][32] ; src = w[(co*CIN + ks*32 + kk)*9 + t]
__global__ void prepack2(const float* __restrict__ src, hf* __restrict__ dst,
                         int COP, int CIN, int NCHn) {
  const int idx = blockIdx.x * 256 + threadIdx.x;
  const int total = 9 * NCHn * COP * 32;
  if (idx >= total) return;
  const int kk = idx & 31;
  const int r = idx >> 5;
  const int co = r % COP;
  const int r2 = r / COP;
  const int ks = r2 % NCHn;
  const int t = r2 / NCHn;
  dst[idx] = (hf)src[((size_t)co * CIN + ks * 32 + kk) * 9 + t];
}

__global__ void dtab1_kernel(const float* __restrict__ w1, float* __restrict__ dtab) {
  const int idx = blockIdx.x * 256 + threadIdx.x;  // 96*9*2
  if (idx >= 96 * 9 * 2) return;
  const int c = idx & 1;
  const int r = idx >> 1;
  const int pat = r % 9;
  const int co = r / 9;
  const int rc = pat / 3, cc = pat % 3;
  const int kh0 = (rc == 0) ? 1 : 0, kh1 = (rc == 2) ? 1 : 2;
  const int kw0 = (cc == 0) ? 1 : 0, kw1 = (cc == 2) ? 1 : 2;
  float s = 0.f;
  for (int kh = kh0; kh <= kh1; ++kh)
    for (int kw = kw0; kw <= kw1; ++kw)
      s += w1[((size_t)(co * 66 + 64 + c) * 3 + kh) * 3 + kw];
  dtab[(co * 9 + pat) * 2 + c] = s;
}

__global__ void dtabE_kernel(const float* __restrict__ e1w, float* __restrict__ dtE) {
  const int co = threadIdx.x;
  if (co < 48) {
    dtE[co * 2 + 0] = e1w[co * 66 + 64];
    dtE[co * 2 + 1] = e1w[co * 66 + 65];
  }
}

// ---------------------------------------------------------------- input builders
__global__ __launch_bounds__(256) void packf1(const float* __restrict__ f1, hf* __restrict__ sA) {
  const int gid = blockIdx.x * 256 + threadIdx.x;  // 2*4096
  const int b = gid >> 12, pix = gid & 4095;
  unsigned words[16];
#pragma unroll
  for (int c = 0; c < 32; c += 2) {
    const float v0 = f1[((size_t)(b * 32 + c)) * 4096 + pix];
    const float v1 = f1[((size_t)(b * 32 + c + 1)) * 4096 + pix];
    words[c >> 1] = (unsigned)f2h_bits(v0) | ((unsigned)f2h_bits(v1) << 16);
  }
  uint4* dst = (uint4*)(sA + (size_t)gid * 32);
#pragma unroll
  for (int i = 0; i < 4; ++i)
    dst[i] = make_uint4(words[4 * i], words[4 * i + 1], words[4 * i + 2], words[4 * i + 3]);
}

__global__ __launch_bounds__(256) void packf2f32(const float* __restrict__ f2,
                                                 float* __restrict__ dst) {
  const int gid = blockIdx.x * 256 + threadIdx.x;  // 2*4096
  const int b = gid >> 12, pix = gid & 4095;
  float* op = dst + (size_t)gid * 32;
#pragma unroll
  for (int c = 0; c < 32; c += 4) {
    float4 v;
    v.x = f2[((size_t)(b * 32 + c + 0)) * 4096 + pix];
    v.y = f2[((size_t)(b * 32 + c + 1)) * 4096 + pix];
    v.z = f2[((size_t)(b * 32 + c + 2)) * 4096 + pix];
    v.w = f2[((size_t)(b * 32 + c + 3)) * 4096 + pix];
    *(float4*)(op + c) = v;
  }
}

__global__ __launch_bounds__(256) void sample2(const float* __restrict__ f2clf,
                                               const float* __restrict__ coords,
                                               hf* __restrict__ f2s) {
  const int gid = blockIdx.x * 256 + threadIdx.x;  // 162*4096
  const int n = gid >> 12, pix = gid & 4095;
  const int b = n / 81, ij = n - b * 81;
  const float di = (float)(ij / 9) - 4.f, dj = (float)(ij % 9) - 4.f;
  const float x = coords[((size_t)(b * 2 + 0)) * 4096 + pix] + di;
  const float y = coords[((size_t)(b * 2 + 1)) * 4096 + pix] + dj;
  const float x0f = floorf(x), y0f = floorf(y);
  const int x0 = (int)x0f, y0 = (int)y0f;
  const float wx1 = x - x0f, wx0 = 1.f - wx1;
  const float wy1 = y - y0f, wy0 = 1.f - wy1;
  const bool vx0 = (unsigned)x0 < 64u, vx1 = (unsigned)(x0 + 1) < 64u;
  const bool vy0 = (unsigned)y0 < 64u, vy1 = (unsigned)(y0 + 1) < 64u;
  const int x0c = min(max(x0, 0), 63), x1c = min(max(x0 + 1, 0), 63);
  const int y0c = min(max(y0, 0), 63), y1c = min(max(y0 + 1, 0), 63);
  const float w00 = (vy0 && vx0) ? wy0 * wx0 : 0.f;
  const float w01 = (vy0 && vx1) ? wy0 * wx1 : 0.f;
  const float w10 = (vy1 && vx0) ? wy1 * wx0 : 0.f;
  const float w11 = (vy1 && vx1) ? wy1 * wx1 : 0.f;
  const float* fb = f2clf + (size_t)b * 4096 * 32;
  const float* p00 = fb + (size_t)(y0c * 64 + x0c) * 32;
  const float* p01 = fb + (size_t)(y0c * 64 + x1c) * 32;
  const float* p10 = fb + (size_t)(y1c * 64 + x0c) * 32;
  const float* p11 = fb + (size_t)(y1c * 64 + x1c) * 32;
  unsigned words[16];
#pragma unroll
  for (int ch = 0; ch < 16; ++ch) {
    const float2 a  = *(const float2*)(p00 + ch * 2);
    const float2 bb = *(const float2*)(p01 + ch * 2);
    const float2 c  = *(const float2*)(p10 + ch * 2);
    const float2 d  = *(const float2*)(p11 + ch * 2);
    const float v0 = w00 * a.x + w01 * bb.x + w10 * c.x + w11 * d.x;
    const float v1 = w00 * a.y + w01 * bb.y + w10 * c.y + w11 * d.y;
    words[ch] = (unsigned)f2h_bits(v0) | ((unsigned)f2h_bits(v1) << 16);
  }
  uint4* dst = (uint4*)(f2s + (size_t)gid * 32);
#pragma unroll
  for (int i = 0; i < 4; ++i)
    dst[i] = make_uint4(words[4 * i], words[4 * i + 1], words[4 * i + 2], words[4 * i + 3]);
}

// ---------------------------------------------------------------- MFMA conv template (round-9 path)
// GEOM: 0 = 3x3 s1 | 1 = 3x3 s2 (64->32) | 2 = deconv parity | 3 = 1x1 (DIRECT, no LDS)
// EPI : 0 = raw store + BN stats | 1 = bias+relu | 2 = bias
template <int GEOM, int EPI, bool DUAL, int G, int KP, int COP, int COB, int MFR,
          int IMGO, int IMGI, int PIXROWS, int WPIX, bool DELTA>
__global__ __launch_bounds__(256) void mconv(
    const hf* __restrict__ src1, const hf* __restrict__ src0,
    const hf* __restrict__ wp, const float* __restrict__ bias,
    const float* __restrict__ dtab, float* __restrict__ statL,
    hf* __restrict__ outB, float* __restrict__ outF) {
  constexpr bool DIRECT = (GEOM == 3);
  constexpr int TAPS  = (GEOM == 2) ? 4 : (GEOM == 3) ? 1 : 9;
  constexpr int TR    = (GEOM == 1) ? (2 * PIXROWS + 1) : (GEOM == 3) ? 1 : (PIXROWS + 2);
  constexpr int TC    = (GEOM == 1) ? 65 : (GEOM == 3) ? 1 : (IMGI + 2);
  constexpr int NSLOT = TR * TC;
  constexpr int PSTR  = NSLOT + 1;
  constexpr int NCH   = KP / 32;
  constexpr int NPIXI = IMGI * IMGI;
  constexpr int NPIXO = (GEOM == 2) ? 4096 : IMGO * IMGO;
  constexpr int NCHUNK = NSLOT * 4;
  constexpr int CPT   = (NCHUNK + 255) / 256;
  constexpr int LDSE  = DIRECT ? 64 : 4 * PSTR * 8;

  __shared__ __align__(16) hf lds[LDSE];

  const int tid = threadIdx.x;
  const int wid = tid >> 6, lane = tid & 63, lg = lane >> 4, ln = lane & 15;
  const int n = blockIdx.z, b = n / 81, ij = n - b * 81;
  const int r0 = blockIdx.x * PIXROWS;
  const int qq = (GEOM == 2) ? (int)(blockIdx.y >> 1) : 0;
  const int pp = (GEOM == 2) ? (int)(blockIdx.y & 1) : 0;
  const int co0 = (GEOM == 2) ? 0 : (int)blockIdx.y * (MFR * 16);

  f32x4 acc[MFR][WPIX];
#pragma unroll
  for (int mf = 0; mf < MFR; ++mf)
#pragma unroll
    for (int pf = 0; pf < WPIX; ++pf) acc[mf][pf] = (f32x4){0.f, 0.f, 0.f, 0.f};

  if constexpr (DIRECT) {
#pragma unroll
    for (int ch = 0; ch < NCH; ++ch) {
      const int k0 = ch * 32;
      h8v afr[MFR];
#pragma unroll
      for (int mf = 0; mf < MFR; ++mf)
        afr[mf] = *(const h8v*)(wp + ((size_t)(co0 + mf * 16 + ln)) * KP + k0 + lg * 8);
#pragma unroll
      for (int pf = 0; pf < WPIX; ++pf) {
        const int pix = r0 * IMGO + wid * (WPIX * 16) + pf * 16 + ln;
        h8v bfr = (h8v){0, 0, 0, 0, 0, 0, 0, 0};
        if (DUAL) {
          bfr = (ch == 0)
              ? *(const h8v*)(src0 + (((size_t)b * NPIXI + pix) * 32 + lg * 8))
              : *(const h8v*)(src1 + (((size_t)n * NPIXI + pix) * 32 + lg * 8));
        } else {
          const int gci = k0 + lg * 8;
          if (gci < G)
            bfr = *(const h8v*)(src1 + (((size_t)n * NPIXI + pix) * G + gci));
        }
#pragma unroll
        for (int mf = 0; mf < MFR; ++mf)
          acc[mf][pf] = __builtin_amdgcn_mfma_f32_16x16x32_f16(afr[mf], bfr, acc[mf][pf], 0, 0, 0);
      }
    }
  } else {
    s8v rbuf[CPT];
    auto stage_load = [&](int k0) {
#pragma unroll
      for (int j = 0; j < CPT; ++j) {
        const int cidx = tid + j * 256;
        s8v v = (s8v){0, 0, 0, 0, 0, 0, 0, 0};
        if (cidx < NCHUNK) {
          const int s = cidx >> 2, p = cidx & 3;
          const int rs = s / TC, cs = s - rs * TC;
          int ir, ic;
          if (GEOM == 1) { ir = 2 * r0 - 1 + rs; ic = (cs < 32) ? 2 * cs : 2 * (cs - 32) - 1; }
          else           { ir = r0 - 1 + rs;     ic = cs - 1; }
          const int gci = k0 + p * 8;
          if (((unsigned)ir < (unsigned)IMGI) && ((unsigned)ic < (unsigned)IMGI)) {
            const int ipix = ir * IMGI + ic;
            if (DUAL) {
              if (gci < 32)
                v = *(const s8v*)(src0 + (((size_t)b * NPIXI + ipix) * 32 + gci));
              else
                v = *(const s8v*)(src1 + (((size_t)n * NPIXI + ipix) * 32 + (gci - 32)));
            } else if (gci < G) {
              v = *(const s8v*)(src1 + (((size_t)n * NPIXI + ipix) * G + gci));
            }
          }
        }
        rbuf[j] = v;
      }
    };
    auto stage_write = [&]() {
#pragma unroll
      for (int j = 0; j < CPT; ++j) {
        const int cidx = tid + j * 256;
        if (cidx < NCHUNK) {
          const int s = cidx >> 2, p = cidx & 3;
          *(s8v*)(&lds[(size_t)(p * PSTR + s) * 8]) = rbuf[j];
        }
      }
    };

    stage_load(0);
#pragma unroll
    for (int ch = 0; ch < NCH; ++ch) {
      if (ch > 0) __syncthreads();
      stage_write();
      __syncthreads();
      if (ch + 1 < NCH) stage_load((ch + 1) * 32);
      const int k0 = ch * 32;
#pragma unroll
      for (int t = 0; t < TAPS; ++t) {
        int dh, dw, wt, kh = 0, kw = 0;
        if (GEOM == 2) {
          dh = qq + (t >> 1) - 1; dw = pp + (t & 1) - 1;
          wt = (qq + 2 * (t >> 1)) * 4 + (pp + 2 * (t & 1));
        } else { kh = t / 3; kw = t % 3; dh = kh - 1; dw = kw - 1; wt = t; }
        h8v afr[MFR];
#pragma unroll
        for (int mf = 0; mf < MFR; ++mf)
          afr[mf] = *(const h8v*)(wp + ((size_t)(wt * COP + co0 + mf * 16 + ln)) * KP + k0 + lg * 8);
#pragma unroll
        for (int pf = 0; pf < WPIX; ++pf) {
          const int pl = wid * (WPIX * 16) + pf * 16 + ln;
          const int rL = pl / IMGO, c = pl - rL * IMGO;
          int slot;
          if (GEOM == 1) slot = (2 * rL + kh) * 65 + ((kw == 1) ? c : (32 + c + (kw >> 1)));
          else           slot = (rL + dh + 1) * TC + (c + dw + 1);
          const h8v bfr = *(const h8v*)(&lds[(size_t)(lg * PSTR + slot) * 8]);
#pragma unroll
          for (int mf = 0; mf < MFR; ++mf)
            acc[mf][pf] = __builtin_amdgcn_mfma_f32_16x16x32_f16(afr[mf], bfr, acc[mf][pf], 0, 0, 0);
        }
      }
    }
  }

  const float di = (float)(ij / 9) - 4.f, dj = (float)(ij % 9) - 4.f;

  {
#pragma unroll
    for (int mf = 0; mf < MFR; ++mf) {
#pragma unroll
      for (int pf = 0; pf < WPIX; ++pf) {
        const int pl = wid * (WPIX * 16) + pf * 16 + ln;
        const int rL = pl / IMGO, c = pl - rL * IMGO;
        int opix;
        if constexpr (GEOM == 2) opix = (2 * (r0 + rL) + qq) * 64 + 2 * c + pp;
        else opix = (r0 + rL) * IMGO + c;
        if constexpr (DELTA && EPI == 0) {
          const int oh = r0 + rL;
          const int rc = (oh == 0) ? 0 : ((oh == IMGO - 1) ? 2 : 1);
          const int cc = (c == 0) ? 0 : ((c == IMGO - 1) ? 2 : 1);
#pragma unroll
          for (int rg = 0; rg < 4; ++rg) {
            const int co = co0 + mf * 16 + lg * 4 + rg;
            acc[mf][pf][rg] += di * dtab[(co * 9 + rc * 3 + cc) * 2 + 0] +
                               dj * dtab[(co * 9 + rc * 3 + cc) * 2 + 1];
          }
        }
        if constexpr (DELTA && EPI == 1) {
#pragma unroll
          for (int rg = 0; rg < 4; ++rg) {
            const int co = co0 + mf * 16 + lg * 4 + rg;
            acc[mf][pf][rg] += di * dtab[co * 2] + dj * dtab[co * 2 + 1];
          }
        }
        if constexpr (EPI == 1 || EPI == 2) {
          const float4 bv = *(const float4*)(bias + co0 + mf * 16 + lg * 4);
          acc[mf][pf][0] += bv.x; acc[mf][pf][1] += bv.y;
          acc[mf][pf][2] += bv.z; acc[mf][pf][3] += bv.w;
          if constexpr (EPI == 1) {
#pragma unroll
            for (int rg = 0; rg < 4; ++rg) acc[mf][pf][rg] = fmaxf(acc[mf][pf][rg], 0.f);
          }
        }
        ushort4 st;
        st.x = f2h_bits(acc[mf][pf][0]); st.y = f2h_bits(acc[mf][pf][1]);
        st.z = f2h_bits(acc[mf][pf][2]); st.w = f2h_bits(acc[mf][pf][3]);
        *reinterpret_cast<ushort4*>(outB + ((size_t)n * NPIXO + opix) * COB + co0 + mf * 16 + lg * 4) = st;
      }
    }
    if constexpr (EPI == 0) {
      __syncthreads();
      float* sl = (float*)lds;
#pragma unroll
      for (int mf = 0; mf < MFR; ++mf) {
#pragma unroll
        for (int rg = 0; rg < 4; ++rg) {
          float s = 0.f, q2 = 0.f;
#pragma unroll
          for (int pf = 0; pf < WPIX; ++pf) {
            const float v = acc[mf][pf][rg];
            s += v; q2 += v * v;
          }
#pragma unroll
          for (int o = 1; o < 16; o <<= 1) { s += __shfl_xor(s, o); q2 += __shfl_xor(q2, o); }
          if (ln == 0) {
            const int cl = mf * 16 + lg * 4 + rg;
            sl[(wid * MFR * 16 + cl) * 2 + 0] = s;
            sl[(wid * MFR * 16 + cl) * 2 + 1] = q2;
          }
        }
      }
      __syncthreads();
      for (int i = tid; i < MFR * 16 * 2; i += 256) {
        const int cl = i >> 1, stt = i & 1;
        float tot = 0.f;
#pragma unroll
        for (int w = 0; w < 4; ++w) tot += sl[(w * MFR * 16 + cl) * 2 + stt];
        atomicAdd(&statL[2 * (co0 + cl) + stt], tot);
      }
    }
  }
  (void)outF;
}

// ---------------------------------------------------------------- mconv2: A/B probe path
// 3x3 s1, 32x32 image, weights staged in LDS per slab from dense [t][ks][co][32] layout.
// Weight LDS is plane-major (chunk-plane p, padded stride) -> 16B-aligned + conflict-free.
// Numerically identical to mconv<0,0,...> (same accumulation order).
template <int G, int COP, int MFR, int PIXROWS, int WPIX>
__global__ __launch_bounds__(256) void mconv2(
    const hf* __restrict__ src1, const hf* __restrict__ wp,
    float* __restrict__ statL, hf* __restrict__ outB) {
  constexpr int IMG = 32;
  constexpr int TAPS = 9;
  constexpr int TC = IMG + 2;        // 34
  constexpr int TR = PIXROWS + 2;    // 6
  constexpr int NSLOT = TR * TC;     // 204
  constexpr int PSTR = NSLOT + 1;    // 205
  constexpr int NCH = G / 32;        // 4
  constexpr int NPIX = IMG * IMG;    // 1024
  constexpr int NCHUNK = NSLOT * 4;  // 816
  constexpr int COT = MFR * 16;      // 64
  constexpr int WPLANE = TAPS * COT; // 576 rows per chunk-plane
  constexpr int WPSTR  = WPLANE + 1; // 577 padded
  constexpr int WCHUNK = WPLANE * 4; // 2304

  __shared__ __align__(16) hf alds[4 * PSTR * 8];
  __shared__ __align__(16) hf wlds[4 * WPSTR * 8];

  const int tid = threadIdx.x;
  const int wid = tid >> 6, lane = tid & 63, lg = lane >> 4, ln = lane & 15;
  const int n = blockIdx.z;
  const int r0 = blockIdx.x * PIXROWS;
  const int co0 = blockIdx.y * COT;

  f32x4 acc[MFR][WPIX];
#pragma unroll
  for (int mf = 0; mf < MFR; ++mf)
#pragma unroll
    for (int pf = 0; pf < WPIX; ++pf) acc[mf][pf] = (f32x4){0.f, 0.f, 0.f, 0.f};

  for (int ks = 0; ks < NCH; ++ks) {
    __syncthreads();
    // activation staging (identical addressing to mconv)
    for (int cidx = tid; cidx < NCHUNK; cidx += 256) {
      const int s = cidx >> 2, p = cidx & 3;
      const int rs = s / TC, cs = s - rs * TC;
      const int ir = r0 - 1 + rs, ic = cs - 1;
      s8v v = (s8v){0, 0, 0, 0, 0, 0, 0, 0};
      if (((unsigned)ir < (unsigned)IMG) && ((unsigned)ic < (unsigned)IMG)) {
        const int ipix = ir * IMG + ic;
        v = *(const s8v*)(src1 + (((size_t)n * NPIX + ipix) * G + ks * 32 + p * 8));
      }
      *(s8v*)(&alds[(size_t)(p * PSTR + s) * 8]) = v;
    }
    // weight staging: dense contiguous global reads, shared by all waves,
    // plane-major LDS (16B aligned chunks, conflict-free)
    for (int widx = tid; widx < WCHUNK; widx += 256) {
      const int p = widx & 3;
      const int r = widx >> 2;            // r = t*COT + co
      const int co = r & (COT - 1);
      const int t = r >> 6;               // COT == 64
      const s8v wv = *(const s8v*)(wp + (((size_t)(t * NCH + ks) * COP + co0 + co) * 32 + p * 8));
      *(s8v*)(&wlds[(size_t)(p * WPSTR + r) * 8]) = wv;
    }
    __syncthreads();
#pragma unroll
    for (int t = 0; t < TAPS; ++t) {
      const int kh = t / 3, kw = t % 3;
      const int dh = kh - 1, dw = kw - 1;
      h8v afr[MFR];
#pragma unroll
      for (int mf = 0; mf < MFR; ++mf)
        afr[mf] = *(const h8v*)(&wlds[(size_t)(lg * WPSTR + t * COT + mf * 16 + ln) * 8]);
#pragma unroll
      for (int pf = 0; pf < WPIX; ++pf) {
        const int pl = wid * (WPIX * 16) + pf * 16 + ln;
        const int rL = pl / IMG, c = pl - rL * IMG;
        const int slot = (rL + dh + 1) * TC + (c + dw + 1);
        const h8v bfr = *(const h8v*)(&alds[(size_t)(lg * PSTR + slot) * 8]);
#pragma unroll
        for (int mf = 0; mf < MFR; ++mf)
          acc[mf][pf] = __builtin_amdgcn_mfma_f32_16x16x32_f16(afr[mf], bfr, acc[mf][pf], 0, 0, 0);
      }
    }
  }

  // epilogue: raw store + BN stats (identical to mconv EPI=0)
#pragma unroll
  for (int mf = 0; mf < MFR; ++mf) {
#pragma unroll
    for (int pf = 0; pf < WPIX; ++pf) {
      const int pl = wid * (WPIX * 16) + pf * 16 + ln;
      const int rL = pl / IMG, c = pl - rL * IMG;
      const int opix = (r0 + rL) * IMG + c;
      ushort4 st;
      st.x = f2h_bits(acc[mf][pf][0]); st.y = f2h_bits(acc[mf][pf][1]);
      st.z = f2h_bits(acc[mf][pf][2]); st.w = f2h_bits(acc[mf][pf][3]);
      *reinterpret_cast<ushort4*>(outB + ((size_t)n * NPIX + opix) * COP + co0 + mf * 16 + lg * 4) = st;
    }
  }
  __syncthreads();
  float* sl = (float*)alds;
#pragma unroll
  for (int mf = 0; mf < MFR; ++mf) {
#pragma unroll
    for (int rg = 0; rg < 4; ++rg) {
      float s = 0.f, q2 = 0.f;
#pragma unroll
      for (int pf = 0; pf < WPIX; ++pf) {
        const float v = acc[mf][pf][rg];
        s += v; q2 += v * v;
      }
#pragma unroll
      for (int o = 1; o < 16; o <<= 1) { s += __shfl_xor(s, o); q2 += __shfl_xor(q2, o); }
      if (ln == 0) {
        const int cl = mf * 16 + lg * 4 + rg;
        sl[(wid * MFR * 16 + cl) * 2 + 0] = s;
        sl[(wid * MFR * 16 + cl) * 2 + 1] = q2;
      }
    }
  }
  __syncthreads();
  for (int i = tid; i < MFR * 16 * 2; i += 256) {
    const int cl = i >> 1, stt = i & 1;
    float tot = 0.f;
#pragma unroll
    for (int w = 0; w < 4; ++w) tot += sl[(w * MFR * 16 + cl) * 2 + stt];
    atomicAdd(&statL[2 * (co0 + cl) + stt], tot);
  }
}

// ---------------------------------------------------------------- BN finalize
__global__ void bnfin_kernel(float* __restrict__ statL, const float* __restrict__ g,
                             const float* __restrict__ bt, int C, float invCnt) {
  const int c = threadIdx.x;
  if (c < C) {
    const float m = statL[2 * c] * invCnt;
    const float var = statL[2 * c + 1] * invCnt - m * m;
    const float sc = g[c] * rsqrtf(var + 1e-5f);
    statL[256 + c] = sc;
    statL[384 + c] = bt[c] - m * sc;
  }
}

// ---------------------------------------------------------------- in-place BN+ReLU
template <int G8>
__global__ __launch_bounds__(256) void norm_ip(hf* __restrict__ x,
                                               const float* __restrict__ statL, long nch) {
  for (long i = (long)blockIdx.x * 256 + threadIdx.x; i < nch; i += (long)gridDim.x * 256) {
    const int ci8 = (int)(i % G8);
    s8v v = *(s8v*)(x + i * 8);
    const f32x4 scA = *(const f32x4*)(statL + 256 + ci8 * 8);
    const f32x4 scB = *(const f32x4*)(statL + 256 + ci8 * 8 + 4);
    const f32x4 shA = *(const f32x4*)(statL + 384 + ci8 * 8);
    const f32x4 shB = *(const f32x4*)(statL + 384 + ci8 * 8 + 4);
    s8v o;
#pragma unroll
    for (int j = 0; j < 8; ++j) {
      const float sc = (j < 4) ? scA[j] : scB[j - 4];
      const float sh = (j < 4) ? shA[j] : shB[j - 4];
      const float f = fmaxf(h2f_bits((unsigned short)v[j]) * sc + sh, 0.f);
      o[j] = (short)f2h_bits(f);
    }
    *(s8v*)(x + i * 8) = o;
  }
}

// ---------------------------------------------------------------- conv5 (CO=1) on VALU
__global__ __launch_bounds__(256) void conv5_kernel(
    const hf* __restrict__ xd, const float* __restrict__ w5, const float* __restrict__ b5,
    float* __restrict__ outp) {
  const int gid = blockIdx.x * 256 + threadIdx.x;  // 162*4096
  const int n = gid >> 12, pix = gid & 4095;
  const int b = n / 81, ij = n - b * 81;
  const int oh = pix >> 6, ow = pix & 63;
  float acc = b5[0];
#pragma unroll
  for (int kh = 0; kh < 3; ++kh) {
    const int ih = oh + kh - 1;
#pragma unroll
    for (int kw = 0; kw < 3; ++kw) {
      const int iw = ow + kw - 1;
      if (((unsigned)ih < 64u) && ((unsigned)iw < 64u)) {
        const hf* xp = xd + ((size_t)n * 4096 + ih * 64 + iw) * 32;
#pragma unroll
        for (int cq = 0; cq < 4; ++cq) {
          const h8v v = *(const h8v*)(xp + cq * 8);
#pragma unroll
          for (int j = 0; j < 8; ++j)
            acc += (float)v[j] * w5[(cq * 8 + j) * 9 + kh * 3 + kw];
        }
      }
    }
  }
  outp[((size_t)(b * 113 + ij)) * 4096 + pix] = acc;
}

// ---------------------------------------------------------------- DAP softmax
__global__ __launch_bounds__(64) void softmax_kernel(
    const float* __restrict__ outp, const float* __restrict__ dapw, float* __restrict__ score) {
  __shared__ float cb[64 * 81];
  __shared__ float sb[64 * 81];
  const int t = threadIdx.x;
  const int gid = blockIdx.x * 64 + t;
  const int b = gid >> 12, hw = gid & 4095;
  for (int d = 0; d < 81; ++d)
    cb[t * 81 + d] = outp[((size_t)(b * 113 + d)) * 4096 + hw];
  float smax = -1e30f;
  for (int o = 0; o < 81; ++o) {
    float s = 0.f;
    const float* dr = dapw + o * 81;
    for (int d = 0; d < 81; ++d) s += dr[d] * cb[t * 81 + d];
    sb[t * 81 + o] = s;
    smax = fmaxf(smax, s);
  }
  float sum = 0.f;
  for (int o = 0; o < 81; ++o) {
    const float e = __expf(sb[t * 81 + o] - smax);
    sb[t * 81 + o] = e;
    sum += e;
  }
  const float inv = 1.f / sum;
  for (int o = 0; o < 81; ++o)
    score[((size_t)(b * 81 + o)) * 4096 + hw] = sb[t * 81 + o] * inv;
}

// ---------------------------------------------------------------- emb reduce
__global__ __launch_bounds__(256) void emb_kernel(
    const float* __restrict__ score, const hf* __restrict__ e3, float* __restrict__ outp) {
  const int idx = blockIdx.x * 256 + threadIdx.x;  // 2*32*4096
  const int b = idx >> 17, r = idx & 131071, m = r >> 12, hw = r & 4095;
  float acc = 0.f;
  for (int d = 0; d < 81; ++d) {
    const float sc = score[((size_t)(b * 81 + d)) * 4096 + hw];
    acc += sc * (float)e3[(((size_t)(b * 81 + d)) * 4096 + hw) * 32 + m];
  }
  outp[((size_t)(b * 113 + 81 + m)) * 4096 + hw] = acc;
}

// ======================================================================
extern "C" void kernel_launch(void* const* d_in, const int* in_sizes, int n_in,
                              void* d_out, int out_size, void* d_ws, size_t ws_size,
                              hipStream_t stream) {
  const float* f1     = (const float*)d_in[0];
  const float* f2     = (const float*)d_in[1];
  const float* coords = (const float*)d_in[2];
  const float* w1     = (const float*)d_in[3];
  const float* g1     = (const float*)d_in[4];
  const float* bb1    = (const float*)d_in[5];
  const float* w2     = (const float*)d_in[6];
  const float* g2     = (const float*)d_in[7];
  const float* bb2    = (const float*)d_in[8];
  const float* w3     = (const float*)d_in[9];
  const float* g3     = (const float*)d_in[10];
  const float* bb3    = (const float*)d_in[11];
  const float* w4     = (const float*)d_in[12];
  const float* g4     = (const float*)d_in[13];
  const float* bb4    = (const float*)d_in[14];
  const float* wdcv   = (const float*)d_in[15];
  const float* gd     = (const float*)d_in[16];
  const float* bbd    = (const float*)d_in[17];
  const float* w5     = (const float*)d_in[18];
  const float* b5     = (const float*)d_in[19];
  const float* e1w    = (const float*)d_in[20];
  const float* e1bi   = (const float*)d_in[21];
  const float* e2w    = (const float*)d_in[22];
  const float* e2bi   = (const float*)d_in[23];
  const float* e3w    = (const float*)d_in[24];
  const float* e3bi   = (const float*)d_in[25];
  const float* dapw   = (const float*)d_in[26];
  float* out = (float*)d_out;
  char* ws = (char*)d_ws;

  hf* sA  = (hf*)(ws + OFF_SA);
  hf* f2s = (hf*)(ws + OFF_F2S);
  hf* be1 = (hf*)(ws + OFF_E1);
  hf* be2 = (hf*)(ws + OFF_E2);
  hf* be3 = (hf*)(ws + OFF_E3);
  hf* x1  = (hf*)(ws + OFF_X1);
  hf* x2  = (hf*)(ws + OFF_X2);
  hf* x3  = (hf*)(ws + OFF_X3);
  hf* x4  = (hf*)(ws + OFF_X4);
  hf* xd  = (hf*)(ws + OFF_XD);
  float* score = (float*)(ws + OFF_SCORE);
  float* stats = (float*)(ws + OFF_STATS);
  hf* wc1 = (hf*)(ws + OFF_WC1);
  hf* wc2 = (hf*)(ws + OFF_WC2);
  hf* wc3 = (hf*)(ws + OFF_WC3);
  hf* wc4 = (hf*)(ws + OFF_WC4);
  hf* wdc = (hf*)(ws + OFF_WDC);
  hf* we1 = (hf*)(ws + OFF_WE1);
  hf* we2 = (hf*)(ws + OFF_WE2);
  hf* we3 = (hf*)(ws + OFF_WE3);
  float* dt1 = (float*)(ws + OFF_DT1);
  float* dtE = (float*)(ws + OFF_DTE);
  float* f2clf = (float*)(ws + OFF_F2CLF);

  hipMemsetAsync(stats, 0, 2560 * sizeof(float), stream);

  // weight prepacks (wc3 uses the dense layout for mconv2)
  prepack<<<216, 256, 0, stream>>>(w1,   wc1, 96, 96, 64, 66, 64, 9);
  prepack<<<432, 256, 0, stream>>>(w2,   wc2, 128, 128, 96, 96, 96, 9);
  prepack2<<<576, 256, 0, stream>>>(w3,  wc3, 128, 128, 4);
  prepack<<<288, 256, 0, stream>>>(w4,   wc4, 64, 64, 128, 128, 128, 9);
  prepack<<<128, 256, 0, stream>>>(wdcv, wdc, 32, 32, 64, 64, 64, 16);
  prepack<<<12,  256, 0, stream>>>(e1w,  we1, 48, 48, 64, 66, 64, 1);
  prepack<<<16,  256, 0, stream>>>(e2w,  we2, 64, 64, 48, 48, 64, 1);
  prepack<<<8,   256, 0, stream>>>(e3w,  we3, 32, 32, 64, 64, 64, 1);
  dtab1_kernel<<<7, 256, 0, stream>>>(w1, dt1);
  dtabE_kernel<<<1, 96, 0, stream>>>(e1w, dtE);

  // inputs (f2 interpolated in fp32)
  packf1<<<32, 256, 0, stream>>>(f1, sA);
  packf2f32<<<32, 256, 0, stream>>>(f2, f2clf);
  sample2<<<2592, 256, 0, stream>>>(f2clf, coords, f2s);

  // embedding branch (DIRECT 1x1 convs)
  mconv<3, 1, true, 32, 64, 48, 48, 3, 64, 64, 4, 4, true>
      <<<dim3(16, 1, 162), 256, 0, stream>>>(f2s, sA, we1, e1bi, dtE, nullptr, be1, nullptr);
  mconv<3, 1, false, 48, 64, 64, 64, 4, 64, 64, 4, 4, false>
      <<<dim3(16, 1, 162), 256, 0, stream>>>(be1, nullptr, we2, e2bi, nullptr, nullptr, be2, nullptr);
  mconv<3, 2, false, 64, 64, 32, 32, 2, 64, 64, 4, 4, false>
      <<<dim3(16, 1, 162), 256, 0, stream>>>(be2, nullptr, we3, e3bi, nullptr, nullptr, be3, nullptr);

  // matching branch
  mconv<0, 0, true, 32, 64, 96, 96, 3, 64, 64, 4, 4, true>
      <<<dim3(16, 2, 162), 256, 0, stream>>>(f2s, sA, wc1, nullptr, dt1, stats + 0, x1, nullptr);
  bnfin_kernel<<<1, 128, 0, stream>>>(stats + 0, g1, bb1, 96, 1.f / 663552.f);
  norm_ip<12><<<2048, 256, 0, stream>>>(x1, stats + 0, 7962624L);

  mconv<1, 0, false, 96, 96, 128, 128, 4, 32, 64, 4, 2, false>
      <<<dim3(8, 2, 162), 256, 0, stream>>>(x1, nullptr, wc2, nullptr, nullptr, stats + 512, x2, nullptr);
  bnfin_kernel<<<1, 128, 0, stream>>>(stats + 512, g2, bb2, 128, 1.f / 165888.f);
  norm_ip<16><<<2048, 256, 0, stream>>>(x2, stats + 512, 2654208L);

  // conv3: A/B probe — mconv2 with LDS-staged dense weights (plane-major, aligned)
  mconv2<128, 128, 4, 4, 2>
      <<<dim3(8, 2, 162), 256, 0, stream>>>(x2, wc3, stats + 1024, x3);
  bnfin_kernel<<<1, 128, 0, stream>>>(stats + 1024, g3, bb3, 128, 1.f / 165888.f);
  norm_ip<16><<<2048, 256, 0, stream>>>(x3, stats + 1024, 2654208L);

  // conv4: unchanged (control for the A/B)
  mconv<0, 0, false, 128, 128, 64, 64, 4, 32, 32, 4, 2, false>
      <<<dim3(8, 1, 162), 256, 0, stream>>>(x3, nullptr, wc4, nullptr, nullptr, stats + 1536, x4, nullptr);
  bnfin_kernel<<<1, 128, 0, stream>>>(stats + 1536, g4, bb4, 64, 1.f / 165888.f);
  norm_ip<8><<<2048, 256, 0, stream>>>(x4, stats + 1536, 1327104L);

  mconv<2, 0, false, 64, 64, 32, 32, 2, 32, 32, 8, 4, false>
      <<<dim3(4, 4, 162), 256, 0, stream>>>(x4, nullptr, wdc, nullptr, nullptr, stats + 2048, xd, nullptr);
  bnfin_kernel<<<1, 128, 0, stream>>>(stats + 2048, gd, bbd, 32, 1.f / 663552.f);
  norm_ip<4><<<2048, 256, 0, stream>>>(xd, stats + 2048, 2654208L);

  // conv5 on VALU (reads normalized xd, fp32 weights) -> cost planes of out
  conv5_kernel<<<2592, 256, 0, stream>>>(xd, w5, b5, out);

  // DAP softmax + embedding reduction
  softmax_kernel<<<128, 64, 0, stream>>>(out, dapw, score);
  emb_kernel<<<1024, 256, 0, stream>>>(score, be3, out);

  (void)in_sizes; (void)n_in; (void)out_size; (void)ws_size;
}

// Round 14
// 984.813 us; speedup vs baseline: 1.3341x; 1.0576x over previous
//
#include <hip/hip_runtime.h>
#include <hip/hip_bf16.h>

typedef _Float16 hf;
typedef short    s8v  __attribute__((ext_vector_type(8)));
typedef _Float16 h8v  __attribute__((ext_vector_type(8)));
typedef float    f32x4 __attribute__((ext_vector_type(4)));

#define DEVINL __device__ __forceinline__

DEVINL unsigned short f2h_bits(float f) { return __builtin_bit_cast(unsigned short, (hf)f); }
DEVINL float h2f_bits(unsigned short u) { return (float)__builtin_bit_cast(hf, u); }

// ---------------------------------------------------------------- arena
static constexpr size_t OFF_SA    = 0;           // f1 packed  [2][4096][32] hf
static constexpr size_t OFF_F2S   = 524288;      // f2 sampled [162][4096][32] hf
static constexpr size_t OFF_E1    = 42991616;    // e1out [162][4096][48]
static constexpr size_t OFF_E2    = 106692608;   // e2out [162][4096][64]
static constexpr size_t OFF_E3    = 42991616;    // e3out [162][4096][32] (reuse E1)
static constexpr size_t OFF_X1    = 85458944;    // x1 [162][4096][96]
static constexpr size_t OFF_X2    = 524288;      // x2 [162][1024][128]
static constexpr size_t OFF_X3    = 85458944;    // x3 [162][1024][128]
static constexpr size_t OFF_X4    = 524288;      // x4 [162][1024][64]
static constexpr size_t OFF_XD    = 127926272;   // xd [162][4096][32]
static constexpr size_t OFF_SCORE = 524288;      // f32 [2][81][4096]
static constexpr size_t OFF_STATS = 212860928;   // f32 2560
static constexpr size_t OFF_WC1   = 212871168;
static constexpr size_t OFF_WC2   = 212981760;
static constexpr size_t OFF_WC3   = 213202944;
static constexpr size_t OFF_WC4   = 213497856;
static constexpr size_t OFF_WDC   = 213645312;
static constexpr size_t OFF_WE1   = 213720064;
static constexpr size_t OFF_WE2   = 213726208;
static constexpr size_t OFF_WE3   = 213734400;
static constexpr size_t OFF_DT1   = 213738496;
static constexpr size_t OFF_DTE   = 213745408;
static constexpr size_t OFF_F2CLF = 213746048;   // f2 packed [2][4096][32] f32 (1 MB)

// ---------------------------------------------------------------- prepack
__global__ void prepack(const float* __restrict__ src, hf* __restrict__ dst,
                        int COr, int COP, int CINr, int CINsrc, int KP, int TAPS) {
  const int idx = blockIdx.x * 256 + threadIdx.x;
  const int total = TAPS * COP * KP;
  if (idx >= total) return;
  const int k = idx % KP;
  const int r = idx / KP;
  const int co = r % COP;
  const int t = r / COP;
  float v = 0.f;
  if (co < COr && k < CINr) v = src[((size_t)co * CINsrc + k) * TAPS + t];
  dst[idx] = (hf)v;
}

// dense layout: dst[t][ks][co][32] ; src = w[(co*CIN + ks*32 + kk)*9 + t]
__global__ void prepack2(const float* __restrict__ src, hf* __restrict__ dst,
                         int COP, int CIN, int NCHn) {
  const int idx = blockIdx.x * 256 + threadIdx.x;
  const int total = 9 * NCHn * COP * 32;
  if (idx >= total) return;
  const int kk = idx & 31;
  const int r = idx >> 5;
  const int co = r % COP;
  const int r2 = r / COP;
  const int ks = r2 % NCHn;
  const int t = r2 / NCHn;
  dst[idx] = (hf)src[((size_t)co * CIN + ks * 32 + kk) * 9 + t];
}

__global__ void dtab1_kernel(const float* __restrict__ w1, float* __restrict__ dtab) {
  const int idx = blockIdx.x * 256 + threadIdx.x;  // 96*9*2
  if (idx >= 96 * 9 * 2) return;
  const int c = idx & 1;
  const int r = idx >> 1;
  const int pat = r % 9;
  const int co = r / 9;
  const int rc = pat / 3, cc = pat % 3;
  const int kh0 = (rc == 0) ? 1 : 0, kh1 = (rc == 2) ? 1 : 2;
  const int kw0 = (cc == 0) ? 1 : 0, kw1 = (cc == 2) ? 1 : 2;
  float s = 0.f;
  for (int kh = kh0; kh <= kh1; ++kh)
    for (int kw = kw0; kw <= kw1; ++kw)
      s += w1[((size_t)(co * 66 + 64 + c) * 3 + kh) * 3 + kw];
  dtab[(co * 9 + pat) * 2 + c] = s;
}

__global__ void dtabE_kernel(const float* __restrict__ e1w, float* __restrict__ dtE) {
  const int co = threadIdx.x;
  if (co < 48) {
    dtE[co * 2 + 0] = e1w[co * 66 + 64];
    dtE[co * 2 + 1] = e1w[co * 66 + 65];
  }
}

// ---------------------------------------------------------------- input builders
__global__ __launch_bounds__(256) void packf1(const float* __restrict__ f1, hf* __restrict__ sA) {
  const int gid = blockIdx.x * 256 + threadIdx.x;  // 2*4096
  const int b = gid >> 12, pix = gid & 4095;
  unsigned words[16];
#pragma unroll
  for (int c = 0; c < 32; c += 2) {
    const float v0 = f1[((size_t)(b * 32 + c)) * 4096 + pix];
    const float v1 = f1[((size_t)(b * 32 + c + 1)) * 4096 + pix];
    words[c >> 1] = (unsigned)f2h_bits(v0) | ((unsigned)f2h_bits(v1) << 16);
  }
  uint4* dst = (uint4*)(sA + (size_t)gid * 32);
#pragma unroll
  for (int i = 0; i < 4; ++i)
    dst[i] = make_uint4(words[4 * i], words[4 * i + 1], words[4 * i + 2], words[4 * i + 3]);
}

__global__ __launch_bounds__(256) void packf2f32(const float* __restrict__ f2,
                                                 float* __restrict__ dst) {
  const int gid = blockIdx.x * 256 + threadIdx.x;  // 2*4096
  const int b = gid >> 12, pix = gid & 4095;
  float* op = dst + (size_t)gid * 32;
#pragma unroll
  for (int c = 0; c < 32; c += 4) {
    float4 v;
    v.x = f2[((size_t)(b * 32 + c + 0)) * 4096 + pix];
    v.y = f2[((size_t)(b * 32 + c + 1)) * 4096 + pix];
    v.z = f2[((size_t)(b * 32 + c + 2)) * 4096 + pix];
    v.w = f2[((size_t)(b * 32 + c + 3)) * 4096 + pix];
    *(float4*)(op + c) = v;
  }
}

__global__ __launch_bounds__(256) void sample2(const float* __restrict__ f2clf,
                                               const float* __restrict__ coords,
                                               hf* __restrict__ f2s) {
  const int gid = blockIdx.x * 256 + threadIdx.x;  // 162*4096
  const int n = gid >> 12, pix = gid & 4095;
  const int b = n / 81, ij = n - b * 81;
  const float di = (float)(ij / 9) - 4.f, dj = (float)(ij % 9) - 4.f;
  const float x = coords[((size_t)(b * 2 + 0)) * 4096 + pix] + di;
  const float y = coords[((size_t)(b * 2 + 1)) * 4096 + pix] + dj;
  const float x0f = floorf(x), y0f = floorf(y);
  const int x0 = (int)x0f, y0 = (int)y0f;
  const float wx1 = x - x0f, wx0 = 1.f - wx1;
  const float wy1 = y - y0f, wy0 = 1.f - wy1;
  const bool vx0 = (unsigned)x0 < 64u, vx1 = (unsigned)(x0 + 1) < 64u;
  const bool vy0 = (unsigned)y0 < 64u, vy1 = (unsigned)(y0 + 1) < 64u;
  const int x0c = min(max(x0, 0), 63), x1c = min(max(x0 + 1, 0), 63);
  const int y0c = min(max(y0, 0), 63), y1c = min(max(y0 + 1, 0), 63);
  const float w00 = (vy0 && vx0) ? wy0 * wx0 : 0.f;
  const float w01 = (vy0 && vx1) ? wy0 * wx1 : 0.f;
  const float w10 = (vy1 && vx0) ? wy1 * wx0 : 0.f;
  const float w11 = (vy1 && vx1) ? wy1 * wx1 : 0.f;
  const float* fb = f2clf + (size_t)b * 4096 * 32;
  const float* p00 = fb + (size_t)(y0c * 64 + x0c) * 32;
  const float* p01 = fb + (size_t)(y0c * 64 + x1c) * 32;
  const float* p10 = fb + (size_t)(y1c * 64 + x0c) * 32;
  const float* p11 = fb + (size_t)(y1c * 64 + x1c) * 32;
  unsigned words[16];
#pragma unroll
  for (int ch = 0; ch < 16; ++ch) {
    const float2 a  = *(const float2*)(p00 + ch * 2);
    const float2 bb = *(const float2*)(p01 + ch * 2);
    const float2 c  = *(const float2*)(p10 + ch * 2);
    const float2 d  = *(const float2*)(p11 + ch * 2);
    const float v0 = w00 * a.x + w01 * bb.x + w10 * c.x + w11 * d.x;
    const float v1 = w00 * a.y + w01 * bb.y + w10 * c.y + w11 * d.y;
    words[ch] = (unsigned)f2h_bits(v0) | ((unsigned)f2h_bits(v1) << 16);
  }
  uint4* dst = (uint4*)(f2s + (size_t)gid * 32);
#pragma unroll
  for (int i = 0; i < 4; ++i)
    dst[i] = make_uint4(words[4 * i], words[4 * i + 1], words[4 * i + 2], words[4 * i + 3]);
}

// ---------------------------------------------------------------- MFMA conv template (round-11 path)
// GEOM: 0 = 3x3 s1 | 1 = 3x3 s2 (64->32) | 2 = deconv parity | 3 = 1x1 (DIRECT, no LDS)
// EPI : 0 = raw store + BN stats | 1 = bias+relu | 2 = bias
template <int GEOM, int EPI, bool DUAL, int G, int KP, int COP, int COB, int MFR,
          int IMGO, int IMGI, int PIXROWS, int WPIX, bool DELTA>
__global__ __launch_bounds__(256) void mconv(
    const hf* __restrict__ src1, const hf* __restrict__ src0,
    const hf* __restrict__ wp, const float* __restrict__ bias,
    const float* __restrict__ dtab, float* __restrict__ statL,
    hf* __restrict__ outB, float* __restrict__ outF) {
  constexpr bool DIRECT = (GEOM == 3);
  constexpr int TAPS  = (GEOM == 2) ? 4 : (GEOM == 3) ? 1 : 9;
  constexpr int TR    = (GEOM == 1) ? (2 * PIXROWS + 1) : (GEOM == 3) ? 1 : (PIXROWS + 2);
  constexpr int TC    = (GEOM == 1) ? 65 : (GEOM == 3) ? 1 : (IMGI + 2);
  constexpr int NSLOT = TR * TC;
  constexpr int PSTR  = NSLOT + 1;
  constexpr int NCH   = KP / 32;
  constexpr int NPIXI = IMGI * IMGI;
  constexpr int NPIXO = (GEOM == 2) ? 4096 : IMGO * IMGO;
  constexpr int NCHUNK = NSLOT * 4;
  constexpr int CPT   = (NCHUNK + 255) / 256;
  constexpr int LDSE  = DIRECT ? 64 : 4 * PSTR * 8;

  __shared__ __align__(16) hf lds[LDSE];

  const int tid = threadIdx.x;
  const int wid = tid >> 6, lane = tid & 63, lg = lane >> 4, ln = lane & 15;
  const int n = blockIdx.z, b = n / 81, ij = n - b * 81;
  const int r0 = blockIdx.x * PIXROWS;
  const int qq = (GEOM == 2) ? (int)(blockIdx.y >> 1) : 0;
  const int pp = (GEOM == 2) ? (int)(blockIdx.y & 1) : 0;
  const int co0 = (GEOM == 2) ? 0 : (int)blockIdx.y * (MFR * 16);

  f32x4 acc[MFR][WPIX];
#pragma unroll
  for (int mf = 0; mf < MFR; ++mf)
#pragma unroll
    for (int pf = 0; pf < WPIX; ++pf) acc[mf][pf] = (f32x4){0.f, 0.f, 0.f, 0.f};

  if constexpr (DIRECT) {
#pragma unroll
    for (int ch = 0; ch < NCH; ++ch) {
      const int k0 = ch * 32;
      h8v afr[MFR];
#pragma unroll
      for (int mf = 0; mf < MFR; ++mf)
        afr[mf] = *(const h8v*)(wp + ((size_t)(co0 + mf * 16 + ln)) * KP + k0 + lg * 8);
#pragma unroll
      for (int pf = 0; pf < WPIX; ++pf) {
        const int pix = r0 * IMGO + wid * (WPIX * 16) + pf * 16 + ln;
        h8v bfr = (h8v){0, 0, 0, 0, 0, 0, 0, 0};
        if (DUAL) {
          bfr = (ch == 0)
              ? *(const h8v*)(src0 + (((size_t)b * NPIXI + pix) * 32 + lg * 8))
              : *(const h8v*)(src1 + (((size_t)n * NPIXI + pix) * 32 + lg * 8));
        } else {
          const int gci = k0 + lg * 8;
          if (gci < G)
            bfr = *(const h8v*)(src1 + (((size_t)n * NPIXI + pix) * G + gci));
        }
#pragma unroll
        for (int mf = 0; mf < MFR; ++mf)
          acc[mf][pf] = __builtin_amdgcn_mfma_f32_16x16x32_f16(afr[mf], bfr, acc[mf][pf], 0, 0, 0);
      }
    }
  } else {
    s8v rbuf[CPT];
    auto stage_load = [&](int k0) {
#pragma unroll
      for (int j = 0; j < CPT; ++j) {
        const int cidx = tid + j * 256;
        s8v v = (s8v){0, 0, 0, 0, 0, 0, 0, 0};
        if (cidx < NCHUNK) {
          const int s = cidx >> 2, p = cidx & 3;
          const int rs = s / TC, cs = s - rs * TC;
          int ir, ic;
          if (GEOM == 1) { ir = 2 * r0 - 1 + rs; ic = (cs < 32) ? 2 * cs : 2 * (cs - 32) - 1; }
          else           { ir = r0 - 1 + rs;     ic = cs - 1; }
          const int gci = k0 + p * 8;
          if (((unsigned)ir < (unsigned)IMGI) && ((unsigned)ic < (unsigned)IMGI)) {
            const int ipix = ir * IMGI + ic;
            if (DUAL) {
              if (gci < 32)
                v = *(const s8v*)(src0 + (((size_t)b * NPIXI + ipix) * 32 + gci));
              else
                v = *(const s8v*)(src1 + (((size_t)n * NPIXI + ipix) * 32 + (gci - 32)));
            } else if (gci < G) {
              v = *(const s8v*)(src1 + (((size_t)n * NPIXI + ipix) * G + gci));
            }
          }
        }
        rbuf[j] = v;
      }
    };
    auto stage_write = [&]() {
#pragma unroll
      for (int j = 0; j < CPT; ++j) {
        const int cidx = tid + j * 256;
        if (cidx < NCHUNK) {
          const int s = cidx >> 2, p = cidx & 3;
          *(s8v*)(&lds[(size_t)(p * PSTR + s) * 8]) = rbuf[j];
        }
      }
    };

    stage_load(0);
#pragma unroll
    for (int ch = 0; ch < NCH; ++ch) {
      if (ch > 0) __syncthreads();
      stage_write();
      __syncthreads();
      if (ch + 1 < NCH) stage_load((ch + 1) * 32);
      const int k0 = ch * 32;
#pragma unroll
      for (int t = 0; t < TAPS; ++t) {
        int dh, dw, wt, kh = 0, kw = 0;
        if (GEOM == 2) {
          dh = qq + (t >> 1) - 1; dw = pp + (t & 1) - 1;
          wt = (qq + 2 * (t >> 1)) * 4 + (pp + 2 * (t & 1));
        } else { kh = t / 3; kw = t % 3; dh = kh - 1; dw = kw - 1; wt = t; }
        h8v afr[MFR];
#pragma unroll
        for (int mf = 0; mf < MFR; ++mf)
          afr[mf] = *(const h8v*)(wp + ((size_t)(wt * COP + co0 + mf * 16 + ln)) * KP + k0 + lg * 8);
#pragma unroll
        for (int pf = 0; pf < WPIX; ++pf) {
          const int pl = wid * (WPIX * 16) + pf * 16 + ln;
          const int rL = pl / IMGO, c = pl - rL * IMGO;
          int slot;
          if (GEOM == 1) slot = (2 * rL + kh) * 65 + ((kw == 1) ? c : (32 + c + (kw >> 1)));
          else           slot = (rL + dh + 1) * TC + (c + dw + 1);
          const h8v bfr = *(const h8v*)(&lds[(size_t)(lg * PSTR + slot) * 8]);
#pragma unroll
          for (int mf = 0; mf < MFR; ++mf)
            acc[mf][pf] = __builtin_amdgcn_mfma_f32_16x16x32_f16(afr[mf], bfr, acc[mf][pf], 0, 0, 0);
        }
      }
    }
  }

  const float di = (float)(ij / 9) - 4.f, dj = (float)(ij % 9) - 4.f;

  {
#pragma unroll
    for (int mf = 0; mf < MFR; ++mf) {
#pragma unroll
      for (int pf = 0; pf < WPIX; ++pf) {
        const int pl = wid * (WPIX * 16) + pf * 16 + ln;
        const int rL = pl / IMGO, c = pl - rL * IMGO;
        int opix;
        if constexpr (GEOM == 2) opix = (2 * (r0 + rL) + qq) * 64 + 2 * c + pp;
        else opix = (r0 + rL) * IMGO + c;
        if constexpr (DELTA && EPI == 0) {
          const int oh = r0 + rL;
          const int rc = (oh == 0) ? 0 : ((oh == IMGO - 1) ? 2 : 1);
          const int cc = (c == 0) ? 0 : ((c == IMGO - 1) ? 2 : 1);
#pragma unroll
          for (int rg = 0; rg < 4; ++rg) {
            const int co = co0 + mf * 16 + lg * 4 + rg;
            acc[mf][pf][rg] += di * dtab[(co * 9 + rc * 3 + cc) * 2 + 0] +
                               dj * dtab[(co * 9 + rc * 3 + cc) * 2 + 1];
          }
        }
        if constexpr (DELTA && EPI == 1) {
#pragma unroll
          for (int rg = 0; rg < 4; ++rg) {
            const int co = co0 + mf * 16 + lg * 4 + rg;
            acc[mf][pf][rg] += di * dtab[co * 2] + dj * dtab[co * 2 + 1];
          }
        }
        if constexpr (EPI == 1 || EPI == 2) {
          const float4 bv = *(const float4*)(bias + co0 + mf * 16 + lg * 4);
          acc[mf][pf][0] += bv.x; acc[mf][pf][1] += bv.y;
          acc[mf][pf][2] += bv.z; acc[mf][pf][3] += bv.w;
          if constexpr (EPI == 1) {
#pragma unroll
            for (int rg = 0; rg < 4; ++rg) acc[mf][pf][rg] = fmaxf(acc[mf][pf][rg], 0.f);
          }
        }
        ushort4 st;
        st.x = f2h_bits(acc[mf][pf][0]); st.y = f2h_bits(acc[mf][pf][1]);
        st.z = f2h_bits(acc[mf][pf][2]); st.w = f2h_bits(acc[mf][pf][3]);
        *reinterpret_cast<ushort4*>(outB + ((size_t)n * NPIXO + opix) * COB + co0 + mf * 16 + lg * 4) = st;
      }
    }
    if constexpr (EPI == 0) {
      __syncthreads();
      float* sl = (float*)lds;
#pragma unroll
      for (int mf = 0; mf < MFR; ++mf) {
#pragma unroll
        for (int rg = 0; rg < 4; ++rg) {
          float s = 0.f, q2 = 0.f;
#pragma unroll
          for (int pf = 0; pf < WPIX; ++pf) {
            const float v = acc[mf][pf][rg];
            s += v; q2 += v * v;
          }
#pragma unroll
          for (int o = 1; o < 16; o <<= 1) { s += __shfl_xor(s, o); q2 += __shfl_xor(q2, o); }
          if (ln == 0) {
            const int cl = mf * 16 + lg * 4 + rg;
            sl[(wid * MFR * 16 + cl) * 2 + 0] = s;
            sl[(wid * MFR * 16 + cl) * 2 + 1] = q2;
          }
        }
      }
      __syncthreads();
      for (int i = tid; i < MFR * 16 * 2; i += 256) {
        const int cl = i >> 1, stt = i & 1;
        float tot = 0.f;
#pragma unroll
        for (int w = 0; w < 4; ++w) tot += sl[(w * MFR * 16 + cl) * 2 + stt];
        atomicAdd(&statL[2 * (co0 + cl) + stt], tot);
      }
    }
  }
  (void)outF;
}

// ---------------------------------------------------------------- mconv2 (round-11 exact)
// 3x3 s1, 32x32 image, weights staged in LDS per slab from dense [t][ks][co][32] layout.
// Weight LDS plane-major (chunk-plane p, padded stride) -> 16B-aligned + conflict-free.
// COT must be 64 (MFR=4).
template <int G, int COP, int MFR, int PIXROWS, int WPIX>
__global__ __launch_bounds__(256) void mconv2(
    const hf* __restrict__ src1, const hf* __restrict__ wp,
    float* __restrict__ statL, hf* __restrict__ outB) {
  constexpr int IMG = 32;
  constexpr int TAPS = 9;
  constexpr int TC = IMG + 2;        // 34
  constexpr int TR = PIXROWS + 2;    // 6
  constexpr int NSLOT = TR * TC;     // 204
  constexpr int PSTR = NSLOT + 1;    // 205
  constexpr int NCH = G / 32;        // 4
  constexpr int NPIX = IMG * IMG;    // 1024
  constexpr int NCHUNK = NSLOT * 4;  // 816
  constexpr int COT = MFR * 16;      // 64
  constexpr int WPLANE = TAPS * COT; // 576 rows per chunk-plane
  constexpr int WPSTR  = WPLANE + 1; // 577 padded
  constexpr int WCHUNK = WPLANE * 4; // 2304

  __shared__ __align__(16) hf alds[4 * PSTR * 8];
  __shared__ __align__(16) hf wlds[4 * WPSTR * 8];

  const int tid = threadIdx.x;
  const int wid = tid >> 6, lane = tid & 63, lg = lane >> 4, ln = lane & 15;
  const int n = blockIdx.z;
  const int r0 = blockIdx.x * PIXROWS;
  const int co0 = blockIdx.y * COT;

  f32x4 acc[MFR][WPIX];
#pragma unroll
  for (int mf = 0; mf < MFR; ++mf)
#pragma unroll
    for (int pf = 0; pf < WPIX; ++pf) acc[mf][pf] = (f32x4){0.f, 0.f, 0.f, 0.f};

  for (int ks = 0; ks < NCH; ++ks) {
    __syncthreads();
    // activation staging (identical addressing to mconv)
    for (int cidx = tid; cidx < NCHUNK; cidx += 256) {
      const int s = cidx >> 2, p = cidx & 3;
      const int rs = s / TC, cs = s - rs * TC;
      const int ir = r0 - 1 + rs, ic = cs - 1;
      s8v v = (s8v){0, 0, 0, 0, 0, 0, 0, 0};
      if (((unsigned)ir < (unsigned)IMG) && ((unsigned)ic < (unsigned)IMG)) {
        const int ipix = ir * IMG + ic;
        v = *(const s8v*)(src1 + (((size_t)n * NPIX + ipix) * G + ks * 32 + p * 8));
      }
      *(s8v*)(&alds[(size_t)(p * PSTR + s) * 8]) = v;
    }
    // weight staging: dense contiguous global reads, shared by all waves,
    // plane-major LDS (16B aligned chunks, conflict-free)
    for (int widx = tid; widx < WCHUNK; widx += 256) {
      const int p = widx & 3;
      const int r = widx >> 2;            // r = t*COT + co
      const int co = r & (COT - 1);
      const int t = r >> 6;               // COT == 64
      const s8v wv = *(const s8v*)(wp + (((size_t)(t * NCH + ks) * COP + co0 + co) * 32 + p * 8));
      *(s8v*)(&wlds[(size_t)(p * WPSTR + r) * 8]) = wv;
    }
    __syncthreads();
#pragma unroll
    for (int t = 0; t < TAPS; ++t) {
      const int kh = t / 3, kw = t % 3;
      const int dh = kh - 1, dw = kw - 1;
      h8v afr[MFR];
#pragma unroll
      for (int mf = 0; mf < MFR; ++mf)
        afr[mf] = *(const h8v*)(&wlds[(size_t)(lg * WPSTR + t * COT + mf * 16 + ln) * 8]);
#pragma unroll
      for (int pf = 0; pf < WPIX; ++pf) {
        const int pl = wid * (WPIX * 16) + pf * 16 + ln;
        const int rL = pl / IMG, c = pl - rL * IMG;
        const int slot = (rL + dh + 1) * TC + (c + dw + 1);
        const h8v bfr = *(const h8v*)(&alds[(size_t)(lg * PSTR + slot) * 8]);
#pragma unroll
        for (int mf = 0; mf < MFR; ++mf)
          acc[mf][pf] = __builtin_amdgcn_mfma_f32_16x16x32_f16(afr[mf], bfr, acc[mf][pf], 0, 0, 0);
      }
    }
  }

  // epilogue: raw store + BN stats
#pragma unroll
  for (int mf = 0; mf < MFR; ++mf) {
#pragma unroll
    for (int pf = 0; pf < WPIX; ++pf) {
      const int pl = wid * (WPIX * 16) + pf * 16 + ln;
      const int rL = pl / IMG, c = pl - rL * IMG;
      const int opix = (r0 + rL) * IMG + c;
      ushort4 st;
      st.x = f2h_bits(acc[mf][pf][0]); st.y = f2h_bits(acc[mf][pf][1]);
      st.z = f2h_bits(acc[mf][pf][2]); st.w = f2h_bits(acc[mf][pf][3]);
      *reinterpret_cast<ushort4*>(outB + ((size_t)n * NPIX + opix) * COP + co0 + mf * 16 + lg * 4) = st;
    }
  }
  __syncthreads();
  float* sl = (float*)alds;
#pragma unroll
  for (int mf = 0; mf < MFR; ++mf) {
#pragma unroll
    for (int rg = 0; rg < 4; ++rg) {
      float s = 0.f, q2 = 0.f;
#pragma unroll
      for (int pf = 0; pf < WPIX; ++pf) {
        const float v = acc[mf][pf][rg];
        s += v; q2 += v * v;
      }
#pragma unroll
      for (int o = 1; o < 16; o <<= 1) { s += __shfl_xor(s, o); q2 += __shfl_xor(q2, o); }
      if (ln == 0) {
        const int cl = mf * 16 + lg * 4 + rg;
        sl[(wid * MFR * 16 + cl) * 2 + 0] = s;
        sl[(wid * MFR * 16 + cl) * 2 + 1] = q2;
      }
    }
  }
  __syncthreads();
  for (int i = tid; i < MFR * 16 * 2; i += 256) {
    const int cl = i >> 1, stt = i & 1;
    float tot = 0.f;
#pragma unroll
    for (int w = 0; w < 4; ++w) tot += sl[(w * MFR * 16 + cl) * 2 + stt];
    atomicAdd(&statL[2 * (co0 + cl) + stt], tot);
  }
}

// ---------------------------------------------------------------- BN finalize
__global__ void bnfin_kernel(float* __restrict__ statL, const float* __restrict__ g,
                             const float* __restrict__ bt, int C, float invCnt) {
  const int c = threadIdx.x;
  if (c < C) {
    const float m = statL[2 * c] * invCnt;
    const float var = statL[2 * c + 1] * invCnt - m * m;
    const float sc = g[c] * rsqrtf(var + 1e-5f);
    statL[256 + c] = sc;
    statL[384 + c] = bt[c] - m * sc;
  }
}

// ---------------------------------------------------------------- in-place BN+ReLU
template <int G8>
__global__ __launch_bounds__(256) void norm_ip(hf* __restrict__ x,
                                               const float* __restrict__ statL, long nch) {
  for (long i = (long)blockIdx.x * 256 + threadIdx.x; i < nch; i += (long)gridDim.x * 256) {
    const int ci8 = (int)(i % G8);
    s8v v = *(s8v*)(x + i * 8);
    const f32x4 scA = *(const f32x4*)(statL + 256 + ci8 * 8);
    const f32x4 scB = *(const f32x4*)(statL + 256 + ci8 * 8 + 4);
    const f32x4 shA = *(const f32x4*)(statL + 384 + ci8 * 8);
    const f32x4 shB = *(const f32x4*)(statL + 384 + ci8 * 8 + 4);
    s8v o;
#pragma unroll
    for (int j = 0; j < 8; ++j) {
      const float sc = (j < 4) ? scA[j] : scB[j - 4];
      const float sh = (j < 4) ? shA[j] : shB[j - 4];
      const float f = fmaxf(h2f_bits((unsigned short)v[j]) * sc + sh, 0.f);
      o[j] = (short)f2h_bits(f);
    }
    *(s8v*)(x + i * 8) = o;
  }
}

// ---------------------------------------------------------------- conv5 (CO=1) on VALU
// reads NORMALIZED xd (post norm_ip), fp32 weights
__global__ __launch_bounds__(256) void conv5_kernel(
    const hf* __restrict__ xd, const float* __restrict__ w5, const float* __restrict__ b5,
    float* __restrict__ outp) {
  const int gid = blockIdx.x * 256 + threadIdx.x;  // 162*4096
  const int n = gid >> 12, pix = gid & 4095;
  const int b = n / 81, ij = n - b * 81;
  const int oh = pix >> 6, ow = pix & 63;
  float acc = b5[0];
#pragma unroll
  for (int kh = 0; kh < 3; ++kh) {
    const int ih = oh + kh - 1;
#pragma unroll
    for (int kw = 0; kw < 3; ++kw) {
      const int iw = ow + kw - 1;
      if (((unsigned)ih < 64u) && ((unsigned)iw < 64u)) {
        const hf* xp = xd + ((size_t)n * 4096 + ih * 64 + iw) * 32;
#pragma unroll
        for (int cq = 0; cq < 4; ++cq) {
          const h8v v = *(const h8v*)(xp + cq * 8);
#pragma unroll
          for (int j = 0; j < 8; ++j)
            acc += (float)v[j] * w5[(cq * 8 + j) * 9 + kh * 3 + kw];
        }
      }
    }
  }
  outp[((size_t)(b * 113 + ij)) * 4096 + pix] = acc;
}

// ---------------------------------------------------------------- DAP softmax
__global__ __launch_bounds__(64) void softmax_kernel(
    const float* __restrict__ outp, const float* __restrict__ dapw, float* __restrict__ score) {
  __shared__ float cb[64 * 81];
  __shared__ float sb[64 * 81];
  const int t = threadIdx.x;
  const int gid = blockIdx.x * 64 + t;
  const int b = gid >> 12, hw = gid & 4095;
  for (int d = 0; d < 81; ++d)
    cb[t * 81 + d] = outp[((size_t)(b * 113 + d)) * 4096 + hw];
  float smax = -1e30f;
  for (int o = 0; o < 81; ++o) {
    float s = 0.f;
    const float* dr = dapw + o * 81;
    for (int d = 0; d < 81; ++d) s += dr[d] * cb[t * 81 + d];
    sb[t * 81 + o] = s;
    smax = fmaxf(smax, s);
  }
  float sum = 0.f;
  for (int o = 0; o < 81; ++o) {
    const float e = __expf(sb[t * 81 + o] - smax);
    sb[t * 81 + o] = e;
    sum += e;
  }
  const float inv = 1.f / sum;
  for (int o = 0; o < 81; ++o)
    score[((size_t)(b * 81 + o)) * 4096 + hw] = sb[t * 81 + o] * inv;
}

// ---------------------------------------------------------------- emb reduce
__global__ __launch_bounds__(256) void emb_kernel(
    const float* __restrict__ score, const hf* __restrict__ e3, float* __restrict__ outp) {
  const int idx = blockIdx.x * 256 + threadIdx.x;  // 2*32*4096
  const int b = idx >> 17, r = idx & 131071, m = r >> 12, hw = r & 4095;
  float acc = 0.f;
  for (int d = 0; d < 81; ++d) {
    const float sc = score[((size_t)(b * 81 + d)) * 4096 + hw];
    acc += sc * (float)e3[(((size_t)(b * 81 + d)) * 4096 + hw) * 32 + m];
  }
  outp[((size_t)(b * 113 + 81 + m)) * 4096 + hw] = acc;
}

// ======================================================================
extern "C" void kernel_launch(void* const* d_in, const int* in_sizes, int n_in,
                              void* d_out, int out_size, void* d_ws, size_t ws_size,
                              hipStream_t stream) {
  const float* f1     = (const float*)d_in[0];
  const float* f2     = (const float*)d_in[1];
  const float* coords = (const float*)d_in[2];
  const float* w1     = (const float*)d_in[3];
  const float* g1     = (const float*)d_in[4];
  const float* bb1    = (const float*)d_in[5];
  const float* w2     = (const float*)d_in[6];
  const float* g2     = (const float*)d_in[7];
  const float* bb2    = (const float*)d_in[8];
  const float* w3     = (const float*)d_in[9];
  const float* g3     = (const float*)d_in[10];
  const float* bb3    = (const float*)d_in[11];
  const float* w4     = (const float*)d_in[12];
  const float* g4     = (const float*)d_in[13];
  const float* bb4    = (const float*)d_in[14];
  const float* wdcv   = (const float*)d_in[15];
  const float* gd     = (const float*)d_in[16];
  const float* bbd    = (const float*)d_in[17];
  const float* w5     = (const float*)d_in[18];
  const float* b5     = (const float*)d_in[19];
  const float* e1w    = (const float*)d_in[20];
  const float* e1bi   = (const float*)d_in[21];
  const float* e2w    = (const float*)d_in[22];
  const float* e2bi   = (const float*)d_in[23];
  const float* e3w    = (const float*)d_in[24];
  const float* e3bi   = (const float*)d_in[25];
  const float* dapw   = (const float*)d_in[26];
  float* out = (float*)d_out;
  char* ws = (char*)d_ws;

  hf* sA  = (hf*)(ws + OFF_SA);
  hf* f2s = (hf*)(ws + OFF_F2S);
  hf* be1 = (hf*)(ws + OFF_E1);
  hf* be2 = (hf*)(ws + OFF_E2);
  hf* be3 = (hf*)(ws + OFF_E3);
  hf* x1  = (hf*)(ws + OFF_X1);
  hf* x2  = (hf*)(ws + OFF_X2);
  hf* x3  = (hf*)(ws + OFF_X3);
  hf* x4  = (hf*)(ws + OFF_X4);
  hf* xd  = (hf*)(ws + OFF_XD);
  float* score = (float*)(ws + OFF_SCORE);
  float* stats = (float*)(ws + OFF_STATS);
  hf* wc1 = (hf*)(ws + OFF_WC1);
  hf* wc2 = (hf*)(ws + OFF_WC2);
  hf* wc3 = (hf*)(ws + OFF_WC3);
  hf* wc4 = (hf*)(ws + OFF_WC4);
  hf* wdc = (hf*)(ws + OFF_WDC);
  hf* we1 = (hf*)(ws + OFF_WE1);
  hf* we2 = (hf*)(ws + OFF_WE2);
  hf* we3 = (hf*)(ws + OFF_WE3);
  float* dt1 = (float*)(ws + OFF_DT1);
  float* dtE = (float*)(ws + OFF_DTE);
  float* f2clf = (float*)(ws + OFF_F2CLF);

  hipMemsetAsync(stats, 0, 2560 * sizeof(float), stream);

  // weight prepacks (round-11 + ONE change: wc4 now dense for mconv2)
  prepack<<<216, 256, 0, stream>>>(w1,   wc1, 96, 96, 64, 66, 64, 9);
  prepack<<<432, 256, 0, stream>>>(w2,   wc2, 128, 128, 96, 96, 96, 9);
  prepack2<<<576, 256, 0, stream>>>(w3,  wc3, 128, 128, 4);
  prepack2<<<288, 256, 0, stream>>>(w4,  wc4, 64, 128, 4);
  prepack<<<128, 256, 0, stream>>>(wdcv, wdc, 32, 32, 64, 64, 64, 16);
  prepack<<<12,  256, 0, stream>>>(e1w,  we1, 48, 48, 64, 66, 64, 1);
  prepack<<<16,  256, 0, stream>>>(e2w,  we2, 64, 64, 48, 48, 64, 1);
  prepack<<<8,   256, 0, stream>>>(e3w,  we3, 32, 32, 64, 64, 64, 1);
  dtab1_kernel<<<7, 256, 0, stream>>>(w1, dt1);
  dtabE_kernel<<<1, 96, 0, stream>>>(e1w, dtE);

  // inputs (f2 interpolated in fp32)
  packf1<<<32, 256, 0, stream>>>(f1, sA);
  packf2f32<<<32, 256, 0, stream>>>(f2, f2clf);
  sample2<<<2592, 256, 0, stream>>>(f2clf, coords, f2s);

  // embedding branch (DIRECT 1x1 convs — round-11 path)
  mconv<3, 1, true, 32, 64, 48, 48, 3, 64, 64, 4, 4, true>
      <<<dim3(16, 1, 162), 256, 0, stream>>>(f2s, sA, we1, e1bi, dtE, nullptr, be1, nullptr);
  mconv<3, 1, false, 48, 64, 64, 64, 4, 64, 64, 4, 4, false>
      <<<dim3(16, 1, 162), 256, 0, stream>>>(be1, nullptr, we2, e2bi, nullptr, nullptr, be2, nullptr);
  mconv<3, 2, false, 64, 64, 32, 32, 2, 64, 64, 4, 4, false>
      <<<dim3(16, 1, 162), 256, 0, stream>>>(be2, nullptr, we3, e3bi, nullptr, nullptr, be3, nullptr);

  // conv1: round-11 path
  mconv<0, 0, true, 32, 64, 96, 96, 3, 64, 64, 4, 4, true>
      <<<dim3(16, 2, 162), 256, 0, stream>>>(f2s, sA, wc1, nullptr, dt1, stats + 0, x1, nullptr);
  bnfin_kernel<<<1, 128, 0, stream>>>(stats + 0, g1, bb1, 96, 1.f / 663552.f);
  norm_ip<12><<<2048, 256, 0, stream>>>(x1, stats + 0, 7962624L);

  // conv2: round-11 path
  mconv<1, 0, false, 96, 96, 128, 128, 4, 32, 64, 4, 2, false>
      <<<dim3(8, 2, 162), 256, 0, stream>>>(x1, nullptr, wc2, nullptr, nullptr, stats + 512, x2, nullptr);
  bnfin_kernel<<<1, 128, 0, stream>>>(stats + 512, g2, bb2, 128, 1.f / 165888.f);
  norm_ip<16><<<2048, 256, 0, stream>>>(x2, stats + 512, 2654208L);

  // conv3: round-11 proven mconv2
  mconv2<128, 128, 4, 4, 2>
      <<<dim3(8, 2, 162), 256, 0, stream>>>(x2, wc3, stats + 1024, x3);
  bnfin_kernel<<<1, 128, 0, stream>>>(stats + 1024, g3, bb3, 128, 1.f / 165888.f);
  norm_ip<16><<<2048, 256, 0, stream>>>(x3, stats + 1024, 2654208L);

  // conv4: THE single new change — same proven template, COP=64
  mconv2<128, 64, 4, 4, 2>
      <<<dim3(8, 1, 162), 256, 0, stream>>>(x3, wc4, stats + 1536, x4);
  bnfin_kernel<<<1, 128, 0, stream>>>(stats + 1536, g4, bb4, 64, 1.f / 165888.f);
  norm_ip<8><<<2048, 256, 0, stream>>>(x4, stats + 1536, 1327104L);

  // deconv: round-11 path
  mconv<2, 0, false, 64, 64, 32, 32, 2, 32, 32, 8, 4, false>
      <<<dim3(4, 4, 162), 256, 0, stream>>>(x4, nullptr, wdc, nullptr, nullptr, stats + 2048, xd, nullptr);
  bnfin_kernel<<<1, 128, 0, stream>>>(stats + 2048, gd, bbd, 32, 1.f / 663552.f);
  norm_ip<4><<<2048, 256, 0, stream>>>(xd, stats + 2048, 2654208L);

  // conv5 on VALU (reads normalized xd, fp32 weights) -> cost planes of out
  conv5_kernel<<<2592, 256, 0, stream>>>(xd, w5, b5, out);

  // DAP softmax + embedding reduction
  softmax_kernel<<<128, 64, 0, stream>>>(out, dapw, score);
  emb_kernel<<<1024, 256, 0, stream>>>(score, be3, out);

  (void)in_sizes; (void)n_in; (void)out_size; (void)ws_size;
}